// Round 2
// baseline (893.953 us; speedup 1.0000x reference)
//
#include <hip/hip_runtime.h>
#include <stdint.h>

// ---------- types ----------
typedef __bf16  bf16x8 __attribute__((ext_vector_type(8)));
typedef short   s16x8  __attribute__((ext_vector_type(8)));
typedef float   f32x4  __attribute__((ext_vector_type(4)));

__device__ inline short f2bf(float f) {
  union { float f; uint32_t u; } v; v.f = f;
  uint32_t r = v.u + 0x7FFFu + ((v.u >> 16) & 1u);   // RNE
  return (short)(r >> 16);
}
__device__ inline uint32_t f2bf_u(float f) { return (uint32_t)(uint16_t)f2bf(f); }

// B=4, H=W=D=16 -> N=4096 tokens/batch, C=512, GROUPS=32 (16 ch/group)

// ---------- GroupNorm stats ----------
__global__ __launch_bounds__(256) void gn_stats_k(const float* __restrict__ x,
                                                  float* __restrict__ mean,
                                                  float* __restrict__ rstd) {
  int bg = blockIdx.x;
  int b = bg >> 5, g = bg & 31;
  int tid = threadIdx.x;
  const float* base = x + (size_t)b * 4096 * 512 + g * 16;
  float s = 0.f, q = 0.f;
  for (int i = tid; i < 16384; i += 256) {
    int n = i >> 2, sub = i & 3;
    float4 v = *(const float4*)(base + (size_t)n * 512 + sub * 4);
    s += v.x + v.y + v.z + v.w;
    q += v.x * v.x + v.y * v.y + v.z * v.z + v.w * v.w;
  }
  for (int off = 32; off > 0; off >>= 1) {
    s += __shfl_down(s, off, 64);
    q += __shfl_down(q, off, 64);
  }
  __shared__ float rs[4], rq[4];
  int w = tid >> 6;
  if ((tid & 63) == 0) { rs[w] = s; rq[w] = q; }
  __syncthreads();
  if (tid == 0) {
    float S = rs[0] + rs[1] + rs[2] + rs[3];
    float Q = rq[0] + rq[1] + rq[2] + rq[3];
    float m = S * (1.f / 65536.f);
    float var = Q * (1.f / 65536.f) - m * m;
    mean[bg] = m;
    rstd[bg] = rsqrtf(var + 1e-6f);
  }
}

// ---------- GN apply -> bf16 h ----------
__global__ __launch_bounds__(256) void gn_apply_k(const float* __restrict__ x,
                                                  const float* __restrict__ mean,
                                                  const float* __restrict__ rstd,
                                                  const float* __restrict__ sc,
                                                  const float* __restrict__ bi,
                                                  short* __restrict__ h) {
  size_t i4 = ((size_t)blockIdx.x * 256 + threadIdx.x) * 4;
  int c = (int)(i4 & 511);
  int tok = (int)(i4 >> 9);
  int b = tok >> 12;
  int bg = b * 32 + (c >> 4);
  float m = mean[bg], r = rstd[bg];
  float4 v = *(const float4*)(x + i4);
  float4 s = *(const float4*)(sc + c);
  float4 bb = *(const float4*)(bi + c);
  short4 o;
  o.x = f2bf((v.x - m) * r * s.x + bb.x);
  o.y = f2bf((v.y - m) * r * s.y + bb.y);
  o.z = f2bf((v.z - m) * r * s.z + bb.z);
  o.w = f2bf((v.w - m) * r * s.w + bb.w);
  *(short4*)(h + i4) = o;
}

// ---------- weights -> bf16, transposed ----------
__global__ __launch_bounds__(256) void wconv_k(const float* __restrict__ wq,
                                               const float* __restrict__ wk,
                                               const float* __restrict__ wv,
                                               const float* __restrict__ wp,
                                               short* __restrict__ wt) {
  int i = blockIdx.x * 256 + threadIdx.x;
  int widx = i >> 18, rem = i & 262143;
  int c = rem >> 9, j = rem & 511;
  const float* w = widx == 0 ? wq : widx == 1 ? wk : widx == 2 ? wv : wp;
  wt[(size_t)widx * 262144 + (size_t)j * 512 + c] = f2bf(w[(size_t)c * 512 + j]);
}

// ---------- GEMM (unchanged, validated) ----------
__global__ __launch_bounds__(256) void gemm_k(const short* __restrict__ A,
                                              const short* __restrict__ Bt,
                                              const float* __restrict__ bias,
                                              const float* __restrict__ xres,
                                              short* __restrict__ outb,
                                              float* __restrict__ outf, int mode) {
  __shared__ __attribute__((aligned(16))) short As[128 * 32];
  __shared__ __attribute__((aligned(16))) short Bs[128 * 32];
  int tid = threadIdx.x;
  int w = tid >> 6, lane = tid & 63, quad = lane >> 4, mrow = lane & 15;
  int wm = w >> 1, wn = w & 1;
  int m0 = blockIdx.x * 128, n0 = blockIdx.y * 128;

  const f32x4 fz = {0.f, 0.f, 0.f, 0.f};
  f32x4 acc[4][4];
#pragma unroll
  for (int i = 0; i < 4; i++)
#pragma unroll
    for (int j = 0; j < 4; j++) acc[i][j] = fz;

  int srow = tid >> 2;
  int scol = (tid & 3) * 8;

  for (int k0 = 0; k0 < 512; k0 += 32) {
    __syncthreads();
#pragma unroll
    for (int i = 0; i < 2; i++) {
      const short* ga = A + (size_t)(m0 + i * 64 + srow) * 512 + k0 + scol;
      const short* gb = Bt + (size_t)(n0 + i * 64 + srow) * 512 + k0 + scol;
      char* la = (char*)As + i * 4096 + w * 1024;
      char* lb = (char*)Bs + i * 4096 + w * 1024;
      __builtin_amdgcn_global_load_lds((__attribute__((address_space(1))) void*)ga,
                                       (__attribute__((address_space(3))) void*)la, 16, 0, 0);
      __builtin_amdgcn_global_load_lds((__attribute__((address_space(1))) void*)gb,
                                       (__attribute__((address_space(3))) void*)lb, 16, 0, 0);
    }
    __syncthreads();
    bf16x8 af[4], bfv[4];
#pragma unroll
    for (int mi = 0; mi < 4; mi++)
      af[mi] = *(const bf16x8*)&As[(wm * 64 + mi * 16 + mrow) * 32 + quad * 8];
#pragma unroll
    for (int ni = 0; ni < 4; ni++)
      bfv[ni] = *(const bf16x8*)&Bs[(wn * 64 + ni * 16 + mrow) * 32 + quad * 8];
#pragma unroll
    for (int mi = 0; mi < 4; mi++)
#pragma unroll
      for (int ni = 0; ni < 4; ni++)
        acc[mi][ni] = __builtin_amdgcn_mfma_f32_16x16x32_bf16(af[mi], bfv[ni], acc[mi][ni], 0, 0, 0);
  }

#pragma unroll
  for (int mi = 0; mi < 4; mi++)
#pragma unroll
    for (int ni = 0; ni < 4; ni++) {
      int col = n0 + wn * 64 + ni * 16 + mrow;
      float bv = bias[col];
#pragma unroll
      for (int r = 0; r < 4; r++) {
        int row = m0 + wm * 64 + mi * 16 + quad * 4 + r;
        float val = acc[mi][ni][r] + bv;
        if (mode == 0) {
          outb[(size_t)row * 512 + col] = f2bf(val);
        } else if (mode == 1) {
          int b = row >> 12, t = row & 4095;
          outb[(size_t)b * (512 * 4096) + (size_t)col * 4096 + t] = f2bf(val);
        } else {
          size_t idx = (size_t)row * 512 + col;
          outf[idx] = xres[idx] + val;
        }
      }
    }
}

// ---------- flash attention v8: 64-key tiles + V direct from L2 + defer-max ----------
// 256 blocks x 8 waves. Wave w: query subtile wq=w&3 (16 q), PV channel group
// g=w>>2 (256 ch). Changes vs v7 (which showed occupancy doubling buys ~5% ->
// stalls are barrier-correlated):
//  * K tile = 64 keys (64 KB, double-buffered = 128 KB LDS): barriers, reduce
//    shuffles, rescale events and convoy overhead all HALVED per key.
//  * V no longer staged in LDS: PV fragments read directly from Vt ([b][c][t]
//    layout, 16B/lane, full 128B-line use across an iter). Loads depend only
//    on t0 -> pipeline under QK/softmax with zero barrier interaction. Kills
//    1/3 of LDS-read traffic and all V staging writes. L2 demand ~2 TB/s/XCD.
//  * Defer-max (THR=8 in log2): rescale only when tile max beats running max
//    by >8 -> ~once per block. P<=256 is safe in f32 accum.
__global__ __launch_bounds__(512, 2) void flash_k(const short* __restrict__ Q,
                                                  const short* __restrict__ K,
                                                  const short* __restrict__ Vt,
                                                  short* __restrict__ O) {
  __shared__ __attribute__((aligned(16))) short Ks[2][32768];   // 2 x 64 KB
  int L = blockIdx.x;
  int b = (L & 7) >> 1;                       // batch -> XCD pair (L%8 round-robin)
  int q0 = (((L >> 3) << 1) | (L & 1)) * 64;
  int tid = threadIdx.x;
  int w = tid >> 6, lane = tid & 63, quad = lane >> 4, m = lane & 15;
  int wq = w & 3;                             // query subtile within block
  int g = w >> 2;                             // PV channel group (0..1)
  const size_t batch_off = (size_t)b * 4096 * 512;
  const float scale2 = 0.06375872f;           // 512^-0.5 * log2(e)

  // Q fragments (B-operand: n=query=lane&15, k=ch=quad*8+j), 16 steps = 512 ch
  const short* Qrow = Q + batch_off + (size_t)(q0 + wq * 16 + m) * 512;
  bf16x8 qf[16];
#pragma unroll
  for (int s = 0; s < 16; s++)
    qf[s] = *(const bf16x8*)&Qrow[s * 32 + quad * 8];

  const f32x4 fz = {0.f, 0.f, 0.f, 0.f};
  f32x4 oacc[16];                             // 256 channels (group g)
#pragma unroll
  for (int i = 0; i < 16; i++) oacc[i] = fz;
  float mrun = -1e30f, lrun = 0.f;

  // V fragment base: row (g*16+ct)*16+m of Vt[b], t offset quad*8 (+t0, +32)
  const short* Vbase = Vt + batch_off + ((size_t)(g * 16) * 16 + m) * 4096 + quad * 8;

  // ---- prologue: stage K tile 0 into buf 0 (64 chunks of 1 KB, 8/wave) ----
#pragma unroll
  for (int i = 0; i < 8; i++) {
    int c8 = w * 8 + i;                       // channel chunk (8 ch = 16B)
    const short* gk = K + batch_off + (size_t)lane * 512 + c8 * 8;
    __builtin_amdgcn_global_load_lds((__attribute__((address_space(1))) void*)gk,
                                     (__attribute__((address_space(3))) void*)&Ks[0][c8 * 512],
                                     16, 0, 0);
  }

#pragma unroll 1
  for (int it = 0; it < 64; ++it) {
    int t0 = it * 64;
    int buf = it & 1;
    __syncthreads();   // staging of buf drained (vmcnt); all waves done with buf^1
    if (it < 63) {
      int t1 = t0 + 64;
#pragma unroll
      for (int i = 0; i < 8; i++) {
        int c8 = w * 8 + i;
        const short* gk = K + batch_off + (size_t)(t1 + lane) * 512 + c8 * 8;
        __builtin_amdgcn_global_load_lds((__attribute__((address_space(1))) void*)gk,
                                         (__attribute__((address_space(3))) void*)&Ks[buf ^ 1][c8 * 512],
                                         16, 0, 0);
      }
    }
    // ---- QK^T: 4 key-blocks of 16, full 512 ch; row=key, col=query ----
    f32x4 sa[4];
#pragma unroll
    for (int kb = 0; kb < 4; kb++) sa[kb] = fz;
#pragma unroll
    for (int s = 0; s < 16; s++) {
      const short* kbase = &Ks[buf][(s * 4 + quad) * 512];
#pragma unroll
      for (int kb = 0; kb < 4; kb++) {
        bf16x8 kf = *(const bf16x8*)&kbase[(kb * 16 + m) * 8];
        sa[kb] = __builtin_amdgcn_mfma_f32_16x16x32_bf16(kf, qf[s], sa[kb], 0, 0, 0);
      }
    }
    // ---- per-lane online softmax (query m, keys kb*16+quad*4+r) ----
    float p[4][4];
    float mx = -1e30f;
#pragma unroll
    for (int kb = 0; kb < 4; kb++)
#pragma unroll
      for (int r = 0; r < 4; r++) {
        p[kb][r] = sa[kb][r] * scale2;
        mx = fmaxf(mx, p[kb][r]);
      }
    mx = fmaxf(mx, __shfl_xor(mx, 16, 64));
    mx = fmaxf(mx, __shfl_xor(mx, 32, 64));
    // defer-max: only bump running max (and rescale O) on a >8 jump
    if (__any(mx > mrun + 8.0f)) {
      float mn = fmaxf(mrun, mx);
      float alpha = exp2f(mrun - mn);
      mrun = mn;
      lrun *= alpha;
      float al[4];
#pragma unroll
      for (int r = 0; r < 4; r++) al[r] = __shfl(alpha, quad * 4 + r, 64);
#pragma unroll
      for (int i = 0; i < 16; i++)
#pragma unroll
        for (int r = 0; r < 4; r++) oacc[i][r] *= al[r];
    }
    float sum = 0.f;
#pragma unroll
    for (int kb = 0; kb < 4; kb++)
#pragma unroll
      for (int r = 0; r < 4; r++) {
        p[kb][r] = exp2f(p[kb][r] - mrun);
        sum += p[kb][r];
      }
    sum += __shfl_xor(sum, 16, 64);
    sum += __shfl_xor(sum, 32, 64);
    lrun += sum;
    // ---- P -> two A-frags (keys 0-31, 32-63): bf16-pair pack, 16 shuffles ----
    uint32_t pkA[4], pkB[4];
#pragma unroll
    for (int r = 0; r < 4; r++) {
      pkA[r] = f2bf_u(p[0][r]) | (f2bf_u(p[1][r]) << 16);
      pkB[r] = f2bf_u(p[2][r]) | (f2bf_u(p[3][r]) << 16);
    }
    s16x8 pa, pb;
#pragma unroll
    for (int j = 0; j < 8; j++) {
      int src = ((((quad & 1) * 2 + (j >> 2)) << 4) | m);
      uint32_t va = (uint32_t)__shfl((int)pkA[j & 3], src, 64);
      uint32_t vb = (uint32_t)__shfl((int)pkB[j & 3], src, 64);
      pa[j] = (short)(quad < 2 ? (va & 0xffffu) : (va >> 16));
      pb[j] = (short)(quad < 2 ? (vb & 0xffffu) : (vb >> 16));
    }
    bf16x8 pf0 = __builtin_bit_cast(bf16x8, pa);
    bf16x8 pf1 = __builtin_bit_cast(bf16x8, pb);
    // ---- O += P @ V, V frags DIRECT from global (L1/L2 served) ----
#pragma unroll
    for (int ct = 0; ct < 16; ct++) {
      const short* vp = Vbase + (size_t)ct * 16 * 4096 + t0;
      bf16x8 vf0 = *(const bf16x8*)vp;
      bf16x8 vf1 = *(const bf16x8*)(vp + 32);
      oacc[ct] = __builtin_amdgcn_mfma_f32_16x16x32_bf16(pf0, vf0, oacc[ct], 0, 0, 0);
      oacc[ct] = __builtin_amdgcn_mfma_f32_16x16x32_bf16(pf1, vf1, oacc[ct], 0, 0, 0);
    }
  }
  // ---- epilogue: O /= l, store bf16 row-major (group g columns) ----
  float invl = 1.f / lrun;
  float ir[4];
#pragma unroll
  for (int r = 0; r < 4; r++) ir[r] = __shfl(invl, quad * 4 + r, 64);
#pragma unroll
  for (int ct = 0; ct < 16; ct++)
#pragma unroll
    for (int r = 0; r < 4; r++) {
      int row = q0 + wq * 16 + quad * 4 + r;
      int col = (g * 16 + ct) * 16 + m;
      O[batch_off + (size_t)row * 512 + col] = f2bf(oacc[ct][r] * ir[r]);
    }
}

extern "C" void kernel_launch(void* const* d_in, const int* in_sizes, int n_in,
                              void* d_out, int out_size, void* d_ws, size_t ws_size,
                              hipStream_t stream) {
  const float* x  = (const float*)d_in[0];
  const float* gs = (const float*)d_in[1];
  const float* gb = (const float*)d_in[2];
  const float* wq = (const float*)d_in[3];
  const float* bq = (const float*)d_in[4];
  const float* wk = (const float*)d_in[5];
  const float* bk = (const float*)d_in[6];
  const float* wv = (const float*)d_in[7];
  const float* bv = (const float*)d_in[8];
  const float* wp = (const float*)d_in[9];
  const float* bp = (const float*)d_in[10];
  float* out = (float*)d_out;

  // ---- workspace layout (~34 MB; Q/K live in d_out until final GEMM) ----
  char* ws = (char*)d_ws;
  float* mean = (float*)ws;                               // 128 f
  float* rstd = (float*)(ws + 512);                       // 128 f
  short* h    = (short*)(ws + 1024);                      // 16384*512 bf16 (16.78 MB)
  short* wt   = (short*)(ws + 1024 + 16777216);           // 4*512*512 bf16 (2 MB)
  short* Vt   = (short*)(ws + 1024 + 16777216 + 2097152); // [b][c][t] bf16 (16.78 MB)
  short* Qb   = (short*)d_out;                            // 16.78 MB in d_out
  short* Kb   = Qb + 8388608;                             // 16.78 MB in d_out
  short* Ob   = h;                                        // alias: h dead after V GEMM

  gn_stats_k<<<128, 256, 0, stream>>>(x, mean, rstd);
  gn_apply_k<<<8192, 256, 0, stream>>>(x, mean, rstd, gs, gb, h);
  wconv_k<<<4096, 256, 0, stream>>>(wq, wk, wv, wp, wt);
  dim3 gg(128, 4);
  gemm_k<<<gg, 256, 0, stream>>>(h, wt,          bq, nullptr, Qb, nullptr, 0);
  gemm_k<<<gg, 256, 0, stream>>>(h, wt + 262144, bk, nullptr, Kb, nullptr, 0);
  gemm_k<<<gg, 256, 0, stream>>>(h, wt + 524288, bv, nullptr, Vt, nullptr, 1);
  flash_k<<<256, 512, 0, stream>>>(Qb, Kb, Vt, Ob);
  // final projection reads Ob (=h space), x, wt_p; writes d_out (overwrites Q/K)
  gemm_k<<<gg, 256, 0, stream>>>(Ob, wt + 786432, bp, x, nullptr, out, 2);
}

// Round 4
// 877.803 us; speedup vs baseline: 1.0184x; 1.0184x over previous
//
#include <hip/hip_runtime.h>
#include <stdint.h>

// ---------- types ----------
typedef __bf16  bf16x8 __attribute__((ext_vector_type(8)));
typedef short   s16x8  __attribute__((ext_vector_type(8)));
typedef float   f32x4  __attribute__((ext_vector_type(4)));
typedef float   f32x16 __attribute__((ext_vector_type(16)));
typedef uint32_t u32x4 __attribute__((ext_vector_type(4)));

__device__ inline short f2bf(float f) {
  union { float f; uint32_t u; } v; v.f = f;
  uint32_t r = v.u + 0x7FFFu + ((v.u >> 16) & 1u);   // RNE
  return (short)(r >> 16);
}

// B=4, H=W=D=16 -> N=4096 tokens/batch, C=512, GROUPS=32 (16 ch/group)

// ---------- GroupNorm stats ----------
__global__ __launch_bounds__(256) void gn_stats_k(const float* __restrict__ x,
                                                  float* __restrict__ mean,
                                                  float* __restrict__ rstd) {
  int bg = blockIdx.x;
  int b = bg >> 5, g = bg & 31;
  int tid = threadIdx.x;
  const float* base = x + (size_t)b * 4096 * 512 + g * 16;
  float s = 0.f, q = 0.f;
  for (int i = tid; i < 16384; i += 256) {
    int n = i >> 2, sub = i & 3;
    float4 v = *(const float4*)(base + (size_t)n * 512 + sub * 4);
    s += v.x + v.y + v.z + v.w;
    q += v.x * v.x + v.y * v.y + v.z * v.z + v.w * v.w;
  }
  for (int off = 32; off > 0; off >>= 1) {
    s += __shfl_down(s, off, 64);
    q += __shfl_down(q, off, 64);
  }
  __shared__ float rs[4], rq[4];
  int w = tid >> 6;
  if ((tid & 63) == 0) { rs[w] = s; rq[w] = q; }
  __syncthreads();
  if (tid == 0) {
    float S = rs[0] + rs[1] + rs[2] + rs[3];
    float Q = rq[0] + rq[1] + rq[2] + rq[3];
    float m = S * (1.f / 65536.f);
    float var = Q * (1.f / 65536.f) - m * m;
    mean[bg] = m;
    rstd[bg] = rsqrtf(var + 1e-6f);
  }
}

// ---------- GN apply -> bf16 h ----------
__global__ __launch_bounds__(256) void gn_apply_k(const float* __restrict__ x,
                                                  const float* __restrict__ mean,
                                                  const float* __restrict__ rstd,
                                                  const float* __restrict__ sc,
                                                  const float* __restrict__ bi,
                                                  short* __restrict__ h) {
  size_t i4 = ((size_t)blockIdx.x * 256 + threadIdx.x) * 4;
  int c = (int)(i4 & 511);
  int tok = (int)(i4 >> 9);
  int b = tok >> 12;
  int bg = b * 32 + (c >> 4);
  float m = mean[bg], r = rstd[bg];
  float4 v = *(const float4*)(x + i4);
  float4 s = *(const float4*)(sc + c);
  float4 bb = *(const float4*)(bi + c);
  short4 o;
  o.x = f2bf((v.x - m) * r * s.x + bb.x);
  o.y = f2bf((v.y - m) * r * s.y + bb.y);
  o.z = f2bf((v.z - m) * r * s.z + bb.z);
  o.w = f2bf((v.w - m) * r * s.w + bb.w);
  *(short4*)(h + i4) = o;
}

// ---------- weights -> bf16, transposed ----------
__global__ __launch_bounds__(256) void wconv_k(const float* __restrict__ wq,
                                               const float* __restrict__ wk,
                                               const float* __restrict__ wv,
                                               const float* __restrict__ wp,
                                               short* __restrict__ wt) {
  int i = blockIdx.x * 256 + threadIdx.x;
  int widx = i >> 18, rem = i & 262143;
  int c = rem >> 9, j = rem & 511;
  const float* w = widx == 0 ? wq : widx == 1 ? wk : widx == 2 ? wv : wp;
  wt[(size_t)widx * 262144 + (size_t)j * 512 + c] = f2bf(w[(size_t)c * 512 + j]);
}

// ---------- GEMM (unchanged, validated) ----------
__global__ __launch_bounds__(256) void gemm_k(const short* __restrict__ A,
                                              const short* __restrict__ Bt,
                                              const float* __restrict__ bias,
                                              const float* __restrict__ xres,
                                              short* __restrict__ outb,
                                              float* __restrict__ outf, int mode) {
  __shared__ __attribute__((aligned(16))) short As[128 * 32];
  __shared__ __attribute__((aligned(16))) short Bs[128 * 32];
  int tid = threadIdx.x;
  int w = tid >> 6, lane = tid & 63, quad = lane >> 4, mrow = lane & 15;
  int wm = w >> 1, wn = w & 1;
  int m0 = blockIdx.x * 128, n0 = blockIdx.y * 128;

  const f32x4 fz = {0.f, 0.f, 0.f, 0.f};
  f32x4 acc[4][4];
#pragma unroll
  for (int i = 0; i < 4; i++)
#pragma unroll
    for (int j = 0; j < 4; j++) acc[i][j] = fz;

  int srow = tid >> 2;
  int scol = (tid & 3) * 8;

  for (int k0 = 0; k0 < 512; k0 += 32) {
    __syncthreads();
#pragma unroll
    for (int i = 0; i < 2; i++) {
      const short* ga = A + (size_t)(m0 + i * 64 + srow) * 512 + k0 + scol;
      const short* gb = Bt + (size_t)(n0 + i * 64 + srow) * 512 + k0 + scol;
      char* la = (char*)As + i * 4096 + w * 1024;
      char* lb = (char*)Bs + i * 4096 + w * 1024;
      __builtin_amdgcn_global_load_lds((__attribute__((address_space(1))) void*)ga,
                                       (__attribute__((address_space(3))) void*)la, 16, 0, 0);
      __builtin_amdgcn_global_load_lds((__attribute__((address_space(1))) void*)gb,
                                       (__attribute__((address_space(3))) void*)lb, 16, 0, 0);
    }
    __syncthreads();
    bf16x8 af[4], bfv[4];
#pragma unroll
    for (int mi = 0; mi < 4; mi++)
      af[mi] = *(const bf16x8*)&As[(wm * 64 + mi * 16 + mrow) * 32 + quad * 8];
#pragma unroll
    for (int ni = 0; ni < 4; ni++)
      bfv[ni] = *(const bf16x8*)&Bs[(wn * 64 + ni * 16 + mrow) * 32 + quad * 8];
#pragma unroll
    for (int mi = 0; mi < 4; mi++)
#pragma unroll
      for (int ni = 0; ni < 4; ni++)
        acc[mi][ni] = __builtin_amdgcn_mfma_f32_16x16x32_bf16(af[mi], bfv[ni], acc[mi][ni], 0, 0, 0);
  }

#pragma unroll
  for (int mi = 0; mi < 4; mi++)
#pragma unroll
    for (int ni = 0; ni < 4; ni++) {
      int col = n0 + wn * 64 + ni * 16 + mrow;
      float bv = bias[col];
#pragma unroll
      for (int r = 0; r < 4; r++) {
        int row = m0 + wm * 64 + mi * 16 + quad * 4 + r;
        float val = acc[mi][ni][r] + bv;
        if (mode == 0) {
          outb[(size_t)row * 512 + col] = f2bf(val);
        } else if (mode == 1) {
          int b = row >> 12, t = row & 4095;
          outb[(size_t)b * (512 * 4096) + (size_t)col * 4096 + t] = f2bf(val);
        } else {
          size_t idx = (size_t)row * 512 + col;
          outf[idx] = xres[idx] + val;
        }
      }
    }
}

// ---------- flash attention v10: v9 (32x32x16, LDS-halved) with shfl-based ----------
// cross-half exchange. v9's absmax failure traced to v_permlane32_swap misuse:
// (a) reduce combine fed it two copies of the SAME value -> compiler may
// coalesce into one VGPR -> degenerate swap (upper-half contribution dropped);
// (b) swap direction semantics unverified for the pack. Both removed: all
// cross-half traffic now __shfl_xor(...,32,64) (alias-safe, validated in
// v7/v8). 10 cross-lane ops/wave-iter (2 reduce + 8 pack) vs v7's 16, and the
// core v9 win stands: one 16B frag feeds 32K FLOP, K-frag reads/CU-iter
// 256->128, V-frag 128->64.
// Layout notes (all robust to any SHARED A/B k-permutation; C-layout is the
// HW-verified crow(r,hi) = (r&3)+8*(r>>2)+4*hi):
//  * QK: A=K (row=key), B=Q (col=query=lane&31); lane owns query ql, 16 keys.
//  * pack: af_ks word w needs keys; own A=(p0,p1) B=(p2,p3) C=(p4,p5) D=(p6,p7)
//    (of p[8ks+..]); w0=hi?Csw:A, w1=hi?Dsw:B, w2=hi?C:Asw, w3=hi?D:Bsw
//    where Xsw = shfl_xor(X,32).
//  * PV: A=P (row=query), B=V (col=channel); defer-max (THR=8, validated v8).
__global__ __launch_bounds__(256, 1) void flash_k(const short* __restrict__ Q,
                                                  const short* __restrict__ K,
                                                  const short* __restrict__ Vt,
                                                  short* __restrict__ O) {
  __shared__ __attribute__((aligned(16))) short Ks[2][16384];   // 2 x 32 KB
  __shared__ __attribute__((aligned(16))) short Vs[2][16384];   // 2 x 32 KB
  int L = blockIdx.x;
  int b = (L & 7) >> 1;                       // batch -> XCD pair (L%8 round-robin)
  int q0 = (((L >> 3) << 1) | (L & 1)) * 64;
  int tid = threadIdx.x;
  int w = tid >> 6, lane = tid & 63;
  int ql = lane & 31, hi = lane >> 5;
  int qh = w & 1, g = w >> 1;                 // query half / channel half
  const size_t batch_off = (size_t)b * 4096 * 512;
  const float scale2 = 0.06375872f;           // 512^-0.5 * log2(e)

  // Q fragments (B-operand 32x32x16: col=query=lane&31, k=hi*8+j), 32 steps
  const short* Qrow = Q + batch_off + (size_t)(q0 + qh * 32 + ql) * 512;
  bf16x8 qf[32];
#pragma unroll
  for (int s = 0; s < 32; s++)
    qf[s] = *(const bf16x8*)&Qrow[s * 16 + hi * 8];

  const f32x16 fz16 = {0,0,0,0,0,0,0,0,0,0,0,0,0,0,0,0};
  f32x16 oacc[8];                             // 32q x 256ch (channel half g)
#pragma unroll
  for (int i = 0; i < 8; i++) oacc[i] = fz16;
  float mrun = -1e30f, lrun = 0.f;

  // ---- prologue: stage K(0), V(0) into buf 0 (frag-major; 8+8 slices/wave) ----
#pragma unroll
  for (int i = 0; i < 8; i++) {
    int s = w * 8 + i;                        // K slice: k-step s, unit=lane
    const short* gk = K + batch_off + (size_t)ql * 512 + s * 16 + hi * 8;
    __builtin_amdgcn_global_load_lds((__attribute__((address_space(1))) void*)gk,
                                     (__attribute__((address_space(3))) void*)&Ks[0][s * 512],
                                     16, 0, 0);
  }
#pragma unroll
  for (int i = 0; i < 8; i++) {
    int j = w * 8 + i;                        // V slice: cb=j>>1, ks=j&1
    const short* gv = Vt + batch_off + (size_t)((j >> 1) * 32 + ql) * 4096 + (j & 1) * 16 + hi * 8;
    __builtin_amdgcn_global_load_lds((__attribute__((address_space(1))) void*)gv,
                                     (__attribute__((address_space(3))) void*)&Vs[0][j * 512],
                                     16, 0, 0);
  }

#pragma unroll 1
  for (int it = 0; it < 128; ++it) {
    int t0 = it * 32;
    int buf = it & 1;
    __syncthreads();   // staging of buf drained (vmcnt); all waves done with buf^1
    if (it < 127) {
      int t1 = t0 + 32;
#pragma unroll
      for (int i = 0; i < 8; i++) {
        int s = w * 8 + i;
        const short* gk = K + batch_off + (size_t)(t1 + ql) * 512 + s * 16 + hi * 8;
        __builtin_amdgcn_global_load_lds((__attribute__((address_space(1))) void*)gk,
                                         (__attribute__((address_space(3))) void*)&Ks[buf ^ 1][s * 512],
                                         16, 0, 0);
      }
#pragma unroll
      for (int i = 0; i < 8; i++) {
        int j = w * 8 + i;
        const short* gv = Vt + batch_off + (size_t)((j >> 1) * 32 + ql) * 4096 + t1 + (j & 1) * 16 + hi * 8;
        __builtin_amdgcn_global_load_lds((__attribute__((address_space(1))) void*)gv,
                                         (__attribute__((address_space(3))) void*)&Vs[buf ^ 1][j * 512],
                                         16, 0, 0);
      }
    }
    // ---- QK^T 32x32: A=K (rows=keys), B=Q (cols=queries); 4 acc chains ----
    f32x16 sc0 = fz16, sc1 = fz16, sc2 = fz16, sc3 = fz16;
#pragma unroll
    for (int s = 0; s < 32; s += 4) {
      bf16x8 k0 = *(const bf16x8*)&Ks[buf][(s + 0) * 512 + lane * 8];
      bf16x8 k1 = *(const bf16x8*)&Ks[buf][(s + 1) * 512 + lane * 8];
      bf16x8 k2 = *(const bf16x8*)&Ks[buf][(s + 2) * 512 + lane * 8];
      bf16x8 k3 = *(const bf16x8*)&Ks[buf][(s + 3) * 512 + lane * 8];
      sc0 = __builtin_amdgcn_mfma_f32_32x32x16_bf16(k0, qf[s + 0], sc0, 0, 0, 0);
      sc1 = __builtin_amdgcn_mfma_f32_32x32x16_bf16(k1, qf[s + 1], sc1, 0, 0, 0);
      sc2 = __builtin_amdgcn_mfma_f32_32x32x16_bf16(k2, qf[s + 2], sc2, 0, 0, 0);
      sc3 = __builtin_amdgcn_mfma_f32_32x32x16_bf16(k3, qf[s + 3], sc3, 0, 0, 0);
    }
    // lane holds: query ql, keys crow(r,hi) = (r&3) + 8*(r>>2) + 4*hi  (16 of 32)
    float pl[16];
#pragma unroll
    for (int r = 0; r < 16; r++)
      pl[r] = (sc0[r] + sc1[r] + sc2[r] + sc3[r]) * scale2;
    // ---- softmax: lane-local 16-key reduce + cross-half shfl combine ----
    float mx = pl[0];
#pragma unroll
    for (int r = 1; r < 16; r++) mx = fmaxf(mx, pl[r]);
    mx = fmaxf(mx, __shfl_xor(mx, 32, 64));
    // defer-max: only bump running max (and rescale O) on a >8 jump
    if (__any(mx > mrun + 8.0f)) {
      float mn = fmaxf(mrun, mx);
      float alpha = exp2f(mrun - mn);
      mrun = mn;
      lrun *= alpha;
      float al[16];
#pragma unroll
      for (int r = 0; r < 16; r++)
        al[r] = __shfl(alpha, (r & 3) + 8 * (r >> 2) + 4 * hi, 64);
#pragma unroll
      for (int cb = 0; cb < 8; cb++)
#pragma unroll
        for (int r = 0; r < 16; r++) oacc[cb][r] *= al[r];
    }
    float p[16];
    float sum = 0.f;
#pragma unroll
    for (int r = 0; r < 16; r++) {
      p[r] = exp2f(pl[r] - mrun);
      sum += p[r];
    }
    sum += __shfl_xor(sum, 32, 64);
    lrun += sum;
    // ---- P -> A-frags: cvt_pk words + word-level shfl_xor exchange ----
    bf16x8 af0, af1;
#pragma unroll
    for (int ks = 0; ks < 2; ks++) {
      uint32_t Aw, Bw, Cw, Dw;
      asm("v_cvt_pk_bf16_f32 %0, %1, %2" : "=v"(Aw) : "v"(p[8 * ks + 0]), "v"(p[8 * ks + 1]));
      asm("v_cvt_pk_bf16_f32 %0, %1, %2" : "=v"(Bw) : "v"(p[8 * ks + 2]), "v"(p[8 * ks + 3]));
      asm("v_cvt_pk_bf16_f32 %0, %1, %2" : "=v"(Cw) : "v"(p[8 * ks + 4]), "v"(p[8 * ks + 5]));
      asm("v_cvt_pk_bf16_f32 %0, %1, %2" : "=v"(Dw) : "v"(p[8 * ks + 6]), "v"(p[8 * ks + 7]));
      uint32_t Asw = (uint32_t)__shfl_xor((int)Aw, 32, 64);
      uint32_t Bsw = (uint32_t)__shfl_xor((int)Bw, 32, 64);
      uint32_t Csw = (uint32_t)__shfl_xor((int)Cw, 32, 64);
      uint32_t Dsw = (uint32_t)__shfl_xor((int)Dw, 32, 64);
      u32x4 u;
      u[0] = hi ? Csw : Aw;
      u[1] = hi ? Dsw : Bw;
      u[2] = hi ? Cw : Asw;
      u[3] = hi ? Dw : Bsw;
      if (ks == 0) af0 = __builtin_bit_cast(bf16x8, u);
      else         af1 = __builtin_bit_cast(bf16x8, u);
    }
    // ---- O += P @ V: A=P (rows=queries), B=V (cols=channels); 8 chains ----
#pragma unroll
    for (int cb = 0; cb < 8; cb++) {
      int jj = (g * 8 + cb) * 2;
      bf16x8 v0 = *(const bf16x8*)&Vs[buf][(jj + 0) * 512 + lane * 8];
      bf16x8 v1 = *(const bf16x8*)&Vs[buf][(jj + 1) * 512 + lane * 8];
      oacc[cb] = __builtin_amdgcn_mfma_f32_32x32x16_bf16(af0, v0, oacc[cb], 0, 0, 0);
      oacc[cb] = __builtin_amdgcn_mfma_f32_32x32x16_bf16(af1, v1, oacc[cb], 0, 0, 0);
    }
  }
  // ---- epilogue: O /= l, store bf16 row-major (rows=queries crow(r,hi)) ----
  float invl = 1.f / lrun;
  float ir[16];
#pragma unroll
  for (int r = 0; r < 16; r++)
    ir[r] = __shfl(invl, (r & 3) + 8 * (r >> 2) + 4 * hi, 64);
#pragma unroll
  for (int cb = 0; cb < 8; cb++) {
    int col = g * 256 + cb * 32 + ql;
#pragma unroll
    for (int r = 0; r < 16; r++) {
      int row = q0 + qh * 32 + (r & 3) + 8 * (r >> 2) + 4 * hi;
      O[batch_off + (size_t)row * 512 + col] = f2bf(oacc[cb][r] * ir[r]);
    }
  }
}

extern "C" void kernel_launch(void* const* d_in, const int* in_sizes, int n_in,
                              void* d_out, int out_size, void* d_ws, size_t ws_size,
                              hipStream_t stream) {
  const float* x  = (const float*)d_in[0];
  const float* gs = (const float*)d_in[1];
  const float* gb = (const float*)d_in[2];
  const float* wq = (const float*)d_in[3];
  const float* bq = (const float*)d_in[4];
  const float* wk = (const float*)d_in[5];
  const float* bk = (const float*)d_in[6];
  const float* wv = (const float*)d_in[7];
  const float* bv = (const float*)d_in[8];
  const float* wp = (const float*)d_in[9];
  const float* bp = (const float*)d_in[10];
  float* out = (float*)d_out;

  // ---- workspace layout (~34 MB; Q/K live in d_out until final GEMM) ----
  char* ws = (char*)d_ws;
  float* mean = (float*)ws;                               // 128 f
  float* rstd = (float*)(ws + 512);                       // 128 f
  short* h    = (short*)(ws + 1024);                      // 16384*512 bf16 (16.78 MB)
  short* wt   = (short*)(ws + 1024 + 16777216);           // 4*512*512 bf16 (2 MB)
  short* Vt   = (short*)(ws + 1024 + 16777216 + 2097152); // [b][c][t] bf16 (16.78 MB)
  short* Qb   = (short*)d_out;                            // 16.78 MB in d_out
  short* Kb   = Qb + 8388608;                             // 16.78 MB in d_out
  short* Ob   = h;                                        // alias: h dead after V GEMM

  gn_stats_k<<<128, 256, 0, stream>>>(x, mean, rstd);
  gn_apply_k<<<8192, 256, 0, stream>>>(x, mean, rstd, gs, gb, h);
  wconv_k<<<4096, 256, 0, stream>>>(wq, wk, wv, wp, wt);
  dim3 gg(128, 4);
  gemm_k<<<gg, 256, 0, stream>>>(h, wt,          bq, nullptr, Qb, nullptr, 0);
  gemm_k<<<gg, 256, 0, stream>>>(h, wt + 262144, bk, nullptr, Kb, nullptr, 0);
  gemm_k<<<gg, 256, 0, stream>>>(h, wt + 524288, bv, nullptr, Vt, nullptr, 1);
  flash_k<<<256, 256, 0, stream>>>(Qb, Kb, Vt, Ob);
  // final projection reads Ob (=h space), x, wt_p; writes d_out (overwrites Q/K)
  gemm_k<<<gg, 256, 0, stream>>>(Ob, wt + 786432, bp, x, nullptr, out, 2);
}

// Round 5
// 713.494 us; speedup vs baseline: 1.2529x; 1.2303x over previous
//
#include <hip/hip_runtime.h>
#include <stdint.h>

// ---------- types ----------
typedef __bf16  bf16x8 __attribute__((ext_vector_type(8)));
typedef short   s16x8  __attribute__((ext_vector_type(8)));
typedef float   f32x4  __attribute__((ext_vector_type(4)));
typedef float   f32x16 __attribute__((ext_vector_type(16)));
typedef uint32_t u32x4 __attribute__((ext_vector_type(4)));

__device__ inline short f2bf(float f) {
  union { float f; uint32_t u; } v; v.f = f;
  uint32_t r = v.u + 0x7FFFu + ((v.u >> 16) & 1u);   // RNE
  return (short)(r >> 16);
}

// B=4, H=W=D=16 -> N=4096 tokens/batch, C=512, GROUPS=32 (16 ch/group)

// ---------- GroupNorm stats ----------
__global__ __launch_bounds__(256) void gn_stats_k(const float* __restrict__ x,
                                                  float* __restrict__ mean,
                                                  float* __restrict__ rstd) {
  int bg = blockIdx.x;
  int b = bg >> 5, g = bg & 31;
  int tid = threadIdx.x;
  const float* base = x + (size_t)b * 4096 * 512 + g * 16;
  float s = 0.f, q = 0.f;
  for (int i = tid; i < 16384; i += 256) {
    int n = i >> 2, sub = i & 3;
    float4 v = *(const float4*)(base + (size_t)n * 512 + sub * 4);
    s += v.x + v.y + v.z + v.w;
    q += v.x * v.x + v.y * v.y + v.z * v.z + v.w * v.w;
  }
  for (int off = 32; off > 0; off >>= 1) {
    s += __shfl_down(s, off, 64);
    q += __shfl_down(q, off, 64);
  }
  __shared__ float rs[4], rq[4];
  int w = tid >> 6;
  if ((tid & 63) == 0) { rs[w] = s; rq[w] = q; }
  __syncthreads();
  if (tid == 0) {
    float S = rs[0] + rs[1] + rs[2] + rs[3];
    float Q = rq[0] + rq[1] + rq[2] + rq[3];
    float m = S * (1.f / 65536.f);
    float var = Q * (1.f / 65536.f) - m * m;
    mean[bg] = m;
    rstd[bg] = rsqrtf(var + 1e-6f);
  }
}

// ---------- GN apply -> bf16 h ----------
__global__ __launch_bounds__(256) void gn_apply_k(const float* __restrict__ x,
                                                  const float* __restrict__ mean,
                                                  const float* __restrict__ rstd,
                                                  const float* __restrict__ sc,
                                                  const float* __restrict__ bi,
                                                  short* __restrict__ h) {
  size_t i4 = ((size_t)blockIdx.x * 256 + threadIdx.x) * 4;
  int c = (int)(i4 & 511);
  int tok = (int)(i4 >> 9);
  int b = tok >> 12;
  int bg = b * 32 + (c >> 4);
  float m = mean[bg], r = rstd[bg];
  float4 v = *(const float4*)(x + i4);
  float4 s = *(const float4*)(sc + c);
  float4 bb = *(const float4*)(bi + c);
  short4 o;
  o.x = f2bf((v.x - m) * r * s.x + bb.x);
  o.y = f2bf((v.y - m) * r * s.y + bb.y);
  o.z = f2bf((v.z - m) * r * s.z + bb.z);
  o.w = f2bf((v.w - m) * r * s.w + bb.w);
  *(short4*)(h + i4) = o;
}

// ---------- weights -> bf16, transposed ----------
__global__ __launch_bounds__(256) void wconv_k(const float* __restrict__ wq,
                                               const float* __restrict__ wk,
                                               const float* __restrict__ wv,
                                               const float* __restrict__ wp,
                                               short* __restrict__ wt) {
  int i = blockIdx.x * 256 + threadIdx.x;
  int widx = i >> 18, rem = i & 262143;
  int c = rem >> 9, j = rem & 511;
  const float* w = widx == 0 ? wq : widx == 1 ? wk : widx == 2 ? wv : wp;
  wt[(size_t)widx * 262144 + (size_t)j * 512 + c] = f2bf(w[(size_t)c * 512 + j]);
}

// ---------- GEMM (unchanged, validated) ----------
__global__ __launch_bounds__(256) void gemm_k(const short* __restrict__ A,
                                              const short* __restrict__ Bt,
                                              const float* __restrict__ bias,
                                              const float* __restrict__ xres,
                                              short* __restrict__ outb,
                                              float* __restrict__ outf, int mode) {
  __shared__ __attribute__((aligned(16))) short As[128 * 32];
  __shared__ __attribute__((aligned(16))) short Bs[128 * 32];
  int tid = threadIdx.x;
  int w = tid >> 6, lane = tid & 63, quad = lane >> 4, mrow = lane & 15;
  int wm = w >> 1, wn = w & 1;
  int m0 = blockIdx.x * 128, n0 = blockIdx.y * 128;

  const f32x4 fz = {0.f, 0.f, 0.f, 0.f};
  f32x4 acc[4][4];
#pragma unroll
  for (int i = 0; i < 4; i++)
#pragma unroll
    for (int j = 0; j < 4; j++) acc[i][j] = fz;

  int srow = tid >> 2;
  int scol = (tid & 3) * 8;

  for (int k0 = 0; k0 < 512; k0 += 32) {
    __syncthreads();
#pragma unroll
    for (int i = 0; i < 2; i++) {
      const short* ga = A + (size_t)(m0 + i * 64 + srow) * 512 + k0 + scol;
      const short* gb = Bt + (size_t)(n0 + i * 64 + srow) * 512 + k0 + scol;
      char* la = (char*)As + i * 4096 + w * 1024;
      char* lb = (char*)Bs + i * 4096 + w * 1024;
      __builtin_amdgcn_global_load_lds((__attribute__((address_space(1))) void*)ga,
                                       (__attribute__((address_space(3))) void*)la, 16, 0, 0);
      __builtin_amdgcn_global_load_lds((__attribute__((address_space(1))) void*)gb,
                                       (__attribute__((address_space(3))) void*)lb, 16, 0, 0);
    }
    __syncthreads();
    bf16x8 af[4], bfv[4];
#pragma unroll
    for (int mi = 0; mi < 4; mi++)
      af[mi] = *(const bf16x8*)&As[(wm * 64 + mi * 16 + mrow) * 32 + quad * 8];
#pragma unroll
    for (int ni = 0; ni < 4; ni++)
      bfv[ni] = *(const bf16x8*)&Bs[(wn * 64 + ni * 16 + mrow) * 32 + quad * 8];
#pragma unroll
    for (int mi = 0; mi < 4; mi++)
#pragma unroll
      for (int ni = 0; ni < 4; ni++)
        acc[mi][ni] = __builtin_amdgcn_mfma_f32_16x16x32_bf16(af[mi], bfv[ni], acc[mi][ni], 0, 0, 0);
  }

#pragma unroll
  for (int mi = 0; mi < 4; mi++)
#pragma unroll
    for (int ni = 0; ni < 4; ni++) {
      int col = n0 + wn * 64 + ni * 16 + mrow;
      float bv = bias[col];
#pragma unroll
      for (int r = 0; r < 4; r++) {
        int row = m0 + wm * 64 + mi * 16 + quad * 4 + r;
        float val = acc[mi][ni][r] + bv;
        if (mode == 0) {
          outb[(size_t)row * 512 + col] = f2bf(val);
        } else if (mode == 1) {
          int b = row >> 12, t = row & 4095;
          outb[(size_t)b * (512 * 4096) + (size_t)col * 4096 + t] = f2bf(val);
        } else {
          size_t idx = (size_t)row * 512 + col;
          outf[idx] = xres[idx] + val;
        }
      }
    }
}

// ---------- flash attention v11: v10 structure, spill-free via k-split QK ----------
// v10 (validated math, but VGPR=256 + spill traffic: qf 128 + oacc 128 = full
// file before QK chains). v11 shrinks both elephants, keeping v10's verified
// QK/softmax/pack/PV/epilogue math byte-identical:
//  * 8 waves (512 thr): w -> qh=w&1 (query half, 32q), gg=w>>1 (128-ch quarter
//    for PV) -> oacc = 4 x f32x16 = 64 VGPR.
//  * k-split QK: wave computes partial S over channels kj*256..+256 (kj=gg&1)
//    -> qf = 16 frags = 64 VGPR. Partner (w^2, same qh, other kj) partials
//    exchanged via 32 KB LDS buffer with raw s_barrier + lgkmcnt(0) ONLY
//    (no __syncthreads -> in-flight K/V prefetch NOT drained mid-iter).
//    QK duplication stays 2x (as v10/v7).
//  * ~220 VGPR -> 2 waves/SIMD, no spill. LDS 64+64+32 = 160 KB (HW max).
// LDS ops/CU-iter ~ 128 K + 64 V + 64 exchange + 64 staging ~ 3.8k cyc vs v7's
// ~6.4k; defer-max (THR=8) validated in v8/v10.
__global__ __launch_bounds__(512, 2) void flash_k(const short* __restrict__ Q,
                                                  const short* __restrict__ K,
                                                  const short* __restrict__ Vt,
                                                  short* __restrict__ O) {
  __shared__ __attribute__((aligned(16))) short Ks[2][16384];   // 64 KB
  __shared__ __attribute__((aligned(16))) short Vs[2][16384];   // 64 KB
  __shared__ __attribute__((aligned(16))) float Sx[8192];       // 32 KB exchange
  int L = blockIdx.x;
  int b = (L & 7) >> 1;                       // batch -> XCD pair (L%8 round-robin)
  int q0 = (((L >> 3) << 1) | (L & 1)) * 64;
  int tid = threadIdx.x;
  int w = tid >> 6, lane = tid & 63;
  int ql = lane & 31, hi = lane >> 5;
  int qh = w & 1;                             // query half (32 queries)
  int gg = w >> 1;                            // PV channel quarter (128 ch)
  int kj = gg & 1;                            // QK k-split half (256 ch)
  const size_t batch_off = (size_t)b * 4096 * 512;
  const float scale2 = 0.06375872f;           // 512^-0.5 * log2(e)

  // Q fragments (B-operand 32x32x16: col=query=ql, k=hi*8+j), 16 steps = half C
  const short* Qrow = Q + batch_off + (size_t)(q0 + qh * 32 + ql) * 512 + kj * 256;
  bf16x8 qf[16];
#pragma unroll
  for (int s = 0; s < 16; s++)
    qf[s] = *(const bf16x8*)&Qrow[s * 16 + hi * 8];

  const f32x16 fz16 = {0,0,0,0,0,0,0,0,0,0,0,0,0,0,0,0};
  f32x16 oacc[4];                             // 32q x 128ch (quarter gg)
#pragma unroll
  for (int i = 0; i < 4; i++) oacc[i] = fz16;
  float mrun = -1e30f, lrun = 0.f;

  // ---- prologue: stage K(0), V(0) into buf 0 (4 K + 4 V slices per wave) ----
#pragma unroll
  for (int i = 0; i < 4; i++) {
    int s = w * 4 + i;                        // K slice = k-step s (1 KB)
    const short* gk = K + batch_off + (size_t)ql * 512 + s * 16 + hi * 8;
    __builtin_amdgcn_global_load_lds((__attribute__((address_space(1))) void*)gk,
                                     (__attribute__((address_space(3))) void*)&Ks[0][s * 512],
                                     16, 0, 0);
  }
#pragma unroll
  for (int i = 0; i < 4; i++) {
    int j = w * 4 + i;                        // V slice: cb=j>>1, ks=j&1 (1 KB)
    const short* gv = Vt + batch_off + (size_t)((j >> 1) * 32 + ql) * 4096 + (j & 1) * 16 + hi * 8;
    __builtin_amdgcn_global_load_lds((__attribute__((address_space(1))) void*)gv,
                                     (__attribute__((address_space(3))) void*)&Vs[0][j * 512],
                                     16, 0, 0);
  }

#pragma unroll 1
  for (int it = 0; it < 128; ++it) {
    int t0 = it * 32;
    int buf = it & 1;
    __syncthreads();   // staging of buf drained (vmcnt); all waves done with buf^1
    if (it < 127) {
      int t1 = t0 + 32;
#pragma unroll
      for (int i = 0; i < 4; i++) {
        int s = w * 4 + i;
        const short* gk = K + batch_off + (size_t)(t1 + ql) * 512 + s * 16 + hi * 8;
        __builtin_amdgcn_global_load_lds((__attribute__((address_space(1))) void*)gk,
                                         (__attribute__((address_space(3))) void*)&Ks[buf ^ 1][s * 512],
                                         16, 0, 0);
      }
#pragma unroll
      for (int i = 0; i < 4; i++) {
        int j = w * 4 + i;
        const short* gv = Vt + batch_off + (size_t)((j >> 1) * 32 + ql) * 4096 + t1 + (j & 1) * 16 + hi * 8;
        __builtin_amdgcn_global_load_lds((__attribute__((address_space(1))) void*)gv,
                                         (__attribute__((address_space(3))) void*)&Vs[buf ^ 1][j * 512],
                                         16, 0, 0);
      }
    }
    // ---- QK^T partial (this wave's 256 channels): A=K rows=keys, B=Q ----
    f32x16 sc0 = fz16, sc1 = fz16;
#pragma unroll
    for (int s = 0; s < 16; s += 2) {
      bf16x8 k0 = *(const bf16x8*)&Ks[buf][(kj * 16 + s + 0) * 512 + lane * 8];
      bf16x8 k1 = *(const bf16x8*)&Ks[buf][(kj * 16 + s + 1) * 512 + lane * 8];
      sc0 = __builtin_amdgcn_mfma_f32_32x32x16_bf16(k0, qf[s + 0], sc0, 0, 0, 0);
      sc1 = __builtin_amdgcn_mfma_f32_32x32x16_bf16(k1, qf[s + 1], sc1, 0, 0, 0);
    }
    // ---- exchange partial S with partner wave (w^2): 4 KB each via Sx ----
    f32x4 c[4];
#pragma unroll
    for (int i = 0; i < 4; i++) {
      c[i][0] = sc0[4 * i + 0] + sc1[4 * i + 0];
      c[i][1] = sc0[4 * i + 1] + sc1[4 * i + 1];
      c[i][2] = sc0[4 * i + 2] + sc1[4 * i + 2];
      c[i][3] = sc0[4 * i + 3] + sc1[4 * i + 3];
      *(f32x4*)&Sx[w * 1024 + i * 256 + lane * 4] = c[i];
    }
    asm volatile("s_waitcnt lgkmcnt(0)" ::: "memory");
    __builtin_amdgcn_s_barrier();               // raw: no vmcnt drain (prefetch stays in flight)
    asm volatile("" ::: "memory");
    // lane holds: query ql, keys crow(r,hi) = (r&3) + 8*(r>>2) + 4*hi
    float pl[16];
#pragma unroll
    for (int i = 0; i < 4; i++) {
      f32x4 d = *(const f32x4*)&Sx[(w ^ 2) * 1024 + i * 256 + lane * 4];
      pl[4 * i + 0] = (c[i][0] + d[0]) * scale2;
      pl[4 * i + 1] = (c[i][1] + d[1]) * scale2;
      pl[4 * i + 2] = (c[i][2] + d[2]) * scale2;
      pl[4 * i + 3] = (c[i][3] + d[3]) * scale2;
    }
    // ---- softmax: lane-local 16-key reduce + cross-half shfl combine ----
    float mx = pl[0];
#pragma unroll
    for (int r = 1; r < 16; r++) mx = fmaxf(mx, pl[r]);
    mx = fmaxf(mx, __shfl_xor(mx, 32, 64));
    // defer-max: only bump running max (and rescale O) on a >8 jump
    if (__any(mx > mrun + 8.0f)) {
      float mn = fmaxf(mrun, mx);
      float alpha = exp2f(mrun - mn);
      mrun = mn;
      lrun *= alpha;
      float al[16];
#pragma unroll
      for (int r = 0; r < 16; r++)
        al[r] = __shfl(alpha, (r & 3) + 8 * (r >> 2) + 4 * hi, 64);
#pragma unroll
      for (int cb = 0; cb < 4; cb++)
#pragma unroll
        for (int r = 0; r < 16; r++) oacc[cb][r] *= al[r];
    }
    float p[16];
    float sum = 0.f;
#pragma unroll
    for (int r = 0; r < 16; r++) {
      p[r] = exp2f(pl[r] - mrun);
      sum += p[r];
    }
    sum += __shfl_xor(sum, 32, 64);
    lrun += sum;
    // ---- P -> A-frags: cvt_pk words + word-level shfl_xor exchange (v10-validated) ----
    bf16x8 af0, af1;
#pragma unroll
    for (int ks = 0; ks < 2; ks++) {
      uint32_t Aw, Bw, Cw, Dw;
      asm("v_cvt_pk_bf16_f32 %0, %1, %2" : "=v"(Aw) : "v"(p[8 * ks + 0]), "v"(p[8 * ks + 1]));
      asm("v_cvt_pk_bf16_f32 %0, %1, %2" : "=v"(Bw) : "v"(p[8 * ks + 2]), "v"(p[8 * ks + 3]));
      asm("v_cvt_pk_bf16_f32 %0, %1, %2" : "=v"(Cw) : "v"(p[8 * ks + 4]), "v"(p[8 * ks + 5]));
      asm("v_cvt_pk_bf16_f32 %0, %1, %2" : "=v"(Dw) : "v"(p[8 * ks + 6]), "v"(p[8 * ks + 7]));
      uint32_t Asw = (uint32_t)__shfl_xor((int)Aw, 32, 64);
      uint32_t Bsw = (uint32_t)__shfl_xor((int)Bw, 32, 64);
      uint32_t Csw = (uint32_t)__shfl_xor((int)Cw, 32, 64);
      uint32_t Dsw = (uint32_t)__shfl_xor((int)Dw, 32, 64);
      u32x4 u;
      u[0] = hi ? Csw : Aw;
      u[1] = hi ? Dsw : Bw;
      u[2] = hi ? Cw : Asw;
      u[3] = hi ? Dw : Bsw;
      if (ks == 0) af0 = __builtin_bit_cast(bf16x8, u);
      else         af1 = __builtin_bit_cast(bf16x8, u);
    }
    // ---- O += P @ V: A=P (rows=queries), B=V (cols=channels); 4 chains ----
#pragma unroll
    for (int cb = 0; cb < 4; cb++) {
      int jj = (gg * 4 + cb) * 2;
      bf16x8 v0 = *(const bf16x8*)&Vs[buf][(jj + 0) * 512 + lane * 8];
      bf16x8 v1 = *(const bf16x8*)&Vs[buf][(jj + 1) * 512 + lane * 8];
      oacc[cb] = __builtin_amdgcn_mfma_f32_32x32x16_bf16(af0, v0, oacc[cb], 0, 0, 0);
      oacc[cb] = __builtin_amdgcn_mfma_f32_32x32x16_bf16(af1, v1, oacc[cb], 0, 0, 0);
    }
  }
  // ---- epilogue: O /= l, store bf16 row-major (rows=queries crow(r,hi)) ----
  float invl = 1.f / lrun;
  float ir[16];
#pragma unroll
  for (int r = 0; r < 16; r++)
    ir[r] = __shfl(invl, (r & 3) + 8 * (r >> 2) + 4 * hi, 64);
#pragma unroll
  for (int cb = 0; cb < 4; cb++) {
    int col = gg * 128 + cb * 32 + ql;
#pragma unroll
    for (int r = 0; r < 16; r++) {
      int row = q0 + qh * 32 + (r & 3) + 8 * (r >> 2) + 4 * hi;
      O[batch_off + (size_t)row * 512 + col] = f2bf(oacc[cb][r] * ir[r]);
    }
  }
}

extern "C" void kernel_launch(void* const* d_in, const int* in_sizes, int n_in,
                              void* d_out, int out_size, void* d_ws, size_t ws_size,
                              hipStream_t stream) {
  const float* x  = (const float*)d_in[0];
  const float* gs = (const float*)d_in[1];
  const float* gb = (const float*)d_in[2];
  const float* wq = (const float*)d_in[3];
  const float* bq = (const float*)d_in[4];
  const float* wk = (const float*)d_in[5];
  const float* bk = (const float*)d_in[6];
  const float* wv = (const float*)d_in[7];
  const float* bv = (const float*)d_in[8];
  const float* wp = (const float*)d_in[9];
  const float* bp = (const float*)d_in[10];
  float* out = (float*)d_out;

  // ---- workspace layout (~34 MB; Q/K live in d_out until final GEMM) ----
  char* ws = (char*)d_ws;
  float* mean = (float*)ws;                               // 128 f
  float* rstd = (float*)(ws + 512);                       // 128 f
  short* h    = (short*)(ws + 1024);                      // 16384*512 bf16 (16.78 MB)
  short* wt   = (short*)(ws + 1024 + 16777216);           // 4*512*512 bf16 (2 MB)
  short* Vt   = (short*)(ws + 1024 + 16777216 + 2097152); // [b][c][t] bf16 (16.78 MB)
  short* Qb   = (short*)d_out;                            // 16.78 MB in d_out
  short* Kb   = Qb + 8388608;                             // 16.78 MB in d_out
  short* Ob   = h;                                        // alias: h dead after V GEMM

  gn_stats_k<<<128, 256, 0, stream>>>(x, mean, rstd);
  gn_apply_k<<<8192, 256, 0, stream>>>(x, mean, rstd, gs, gb, h);
  wconv_k<<<4096, 256, 0, stream>>>(wq, wk, wv, wp, wt);
  dim3 gg(128, 4);
  gemm_k<<<gg, 256, 0, stream>>>(h, wt,          bq, nullptr, Qb, nullptr, 0);
  gemm_k<<<gg, 256, 0, stream>>>(h, wt + 262144, bk, nullptr, Kb, nullptr, 0);
  gemm_k<<<gg, 256, 0, stream>>>(h, wt + 524288, bv, nullptr, Vt, nullptr, 1);
  flash_k<<<256, 512, 0, stream>>>(Qb, Kb, Vt, Ob);
  // final projection reads Ob (=h space), x, wt_p; writes d_out (overwrites Q/K)
  gemm_k<<<gg, 256, 0, stream>>>(Ob, wt + 786432, bp, x, nullptr, out, 2);
}

// Round 6
// 655.759 us; speedup vs baseline: 1.3632x; 1.0880x over previous
//
#include <hip/hip_runtime.h>
#include <stdint.h>

// ---------- types ----------
typedef __bf16  bf16x8 __attribute__((ext_vector_type(8)));
typedef short   s16x8  __attribute__((ext_vector_type(8)));
typedef float   f32x4  __attribute__((ext_vector_type(4)));
typedef float   f32x16 __attribute__((ext_vector_type(16)));
typedef uint32_t u32x4 __attribute__((ext_vector_type(4)));

__device__ inline short f2bf(float f) {
  union { float f; uint32_t u; } v; v.f = f;
  uint32_t r = v.u + 0x7FFFu + ((v.u >> 16) & 1u);   // RNE
  return (short)(r >> 16);
}

// B=4, H=W=D=16 -> N=4096 tokens/batch, C=512, GROUPS=32 (16 ch/group)

// ---------- GroupNorm stats ----------
__global__ __launch_bounds__(256) void gn_stats_k(const float* __restrict__ x,
                                                  float* __restrict__ mean,
                                                  float* __restrict__ rstd) {
  int bg = blockIdx.x;
  int b = bg >> 5, g = bg & 31;
  int tid = threadIdx.x;
  const float* base = x + (size_t)b * 4096 * 512 + g * 16;
  float s = 0.f, q = 0.f;
  for (int i = tid; i < 16384; i += 256) {
    int n = i >> 2, sub = i & 3;
    float4 v = *(const float4*)(base + (size_t)n * 512 + sub * 4);
    s += v.x + v.y + v.z + v.w;
    q += v.x * v.x + v.y * v.y + v.z * v.z + v.w * v.w;
  }
  for (int off = 32; off > 0; off >>= 1) {
    s += __shfl_down(s, off, 64);
    q += __shfl_down(q, off, 64);
  }
  __shared__ float rs[4], rq[4];
  int w = tid >> 6;
  if ((tid & 63) == 0) { rs[w] = s; rq[w] = q; }
  __syncthreads();
  if (tid == 0) {
    float S = rs[0] + rs[1] + rs[2] + rs[3];
    float Q = rq[0] + rq[1] + rq[2] + rq[3];
    float m = S * (1.f / 65536.f);
    float var = Q * (1.f / 65536.f) - m * m;
    mean[bg] = m;
    rstd[bg] = rsqrtf(var + 1e-6f);
  }
}

// ---------- GN apply -> bf16 h ----------
__global__ __launch_bounds__(256) void gn_apply_k(const float* __restrict__ x,
                                                  const float* __restrict__ mean,
                                                  const float* __restrict__ rstd,
                                                  const float* __restrict__ sc,
                                                  const float* __restrict__ bi,
                                                  short* __restrict__ h) {
  size_t i4 = ((size_t)blockIdx.x * 256 + threadIdx.x) * 4;
  int c = (int)(i4 & 511);
  int tok = (int)(i4 >> 9);
  int b = tok >> 12;
  int bg = b * 32 + (c >> 4);
  float m = mean[bg], r = rstd[bg];
  float4 v = *(const float4*)(x + i4);
  float4 s = *(const float4*)(sc + c);
  float4 bb = *(const float4*)(bi + c);
  short4 o;
  o.x = f2bf((v.x - m) * r * s.x + bb.x);
  o.y = f2bf((v.y - m) * r * s.y + bb.y);
  o.z = f2bf((v.z - m) * r * s.z + bb.z);
  o.w = f2bf((v.w - m) * r * s.w + bb.w);
  *(short4*)(h + i4) = o;
}

// ---------- weights -> bf16, transposed ----------
__global__ __launch_bounds__(256) void wconv_k(const float* __restrict__ wq,
                                               const float* __restrict__ wk,
                                               const float* __restrict__ wv,
                                               const float* __restrict__ wp,
                                               short* __restrict__ wt) {
  int i = blockIdx.x * 256 + threadIdx.x;
  int widx = i >> 18, rem = i & 262143;
  int c = rem >> 9, j = rem & 511;
  const float* w = widx == 0 ? wq : widx == 1 ? wk : widx == 2 ? wv : wp;
  wt[(size_t)widx * 262144 + (size_t)j * 512 + c] = f2bf(w[(size_t)c * 512 + j]);
}

// ---------- GEMM (unchanged, validated) ----------
__global__ __launch_bounds__(256) void gemm_k(const short* __restrict__ A,
                                              const short* __restrict__ Bt,
                                              const float* __restrict__ bias,
                                              const float* __restrict__ xres,
                                              short* __restrict__ outb,
                                              float* __restrict__ outf, int mode) {
  __shared__ __attribute__((aligned(16))) short As[128 * 32];
  __shared__ __attribute__((aligned(16))) short Bs[128 * 32];
  int tid = threadIdx.x;
  int w = tid >> 6, lane = tid & 63, quad = lane >> 4, mrow = lane & 15;
  int wm = w >> 1, wn = w & 1;
  int m0 = blockIdx.x * 128, n0 = blockIdx.y * 128;

  const f32x4 fz = {0.f, 0.f, 0.f, 0.f};
  f32x4 acc[4][4];
#pragma unroll
  for (int i = 0; i < 4; i++)
#pragma unroll
    for (int j = 0; j < 4; j++) acc[i][j] = fz;

  int srow = tid >> 2;
  int scol = (tid & 3) * 8;

  for (int k0 = 0; k0 < 512; k0 += 32) {
    __syncthreads();
#pragma unroll
    for (int i = 0; i < 2; i++) {
      const short* ga = A + (size_t)(m0 + i * 64 + srow) * 512 + k0 + scol;
      const short* gb = Bt + (size_t)(n0 + i * 64 + srow) * 512 + k0 + scol;
      char* la = (char*)As + i * 4096 + w * 1024;
      char* lb = (char*)Bs + i * 4096 + w * 1024;
      __builtin_amdgcn_global_load_lds((__attribute__((address_space(1))) void*)ga,
                                       (__attribute__((address_space(3))) void*)la, 16, 0, 0);
      __builtin_amdgcn_global_load_lds((__attribute__((address_space(1))) void*)gb,
                                       (__attribute__((address_space(3))) void*)lb, 16, 0, 0);
    }
    __syncthreads();
    bf16x8 af[4], bfv[4];
#pragma unroll
    for (int mi = 0; mi < 4; mi++)
      af[mi] = *(const bf16x8*)&As[(wm * 64 + mi * 16 + mrow) * 32 + quad * 8];
#pragma unroll
    for (int ni = 0; ni < 4; ni++)
      bfv[ni] = *(const bf16x8*)&Bs[(wn * 64 + ni * 16 + mrow) * 32 + quad * 8];
#pragma unroll
    for (int mi = 0; mi < 4; mi++)
#pragma unroll
      for (int ni = 0; ni < 4; ni++)
        acc[mi][ni] = __builtin_amdgcn_mfma_f32_16x16x32_bf16(af[mi], bfv[ni], acc[mi][ni], 0, 0, 0);
  }

#pragma unroll
  for (int mi = 0; mi < 4; mi++)
#pragma unroll
    for (int ni = 0; ni < 4; ni++) {
      int col = n0 + wn * 64 + ni * 16 + mrow;
      float bv = bias[col];
#pragma unroll
      for (int r = 0; r < 4; r++) {
        int row = m0 + wm * 64 + mi * 16 + quad * 4 + r;
        float val = acc[mi][ni][r] + bv;
        if (mode == 0) {
          outb[(size_t)row * 512 + col] = f2bf(val);
        } else if (mode == 1) {
          int b = row >> 12, t = row & 4095;
          outb[(size_t)b * (512 * 4096) + (size_t)col * 4096 + t] = f2bf(val);
        } else {
          size_t idx = (size_t)row * 512 + col;
          outf[idx] = xres[idx] + val;
        }
      }
    }
}

// ---------- flash attention v12: v11 + V direct-to-REGISTERS (T14 async-stage) ----------
// v11 diagnosis: wall ~= serial sum of DS(~3.4k) + VALU(~2.2k) + MFMA(~1.6k)
// cyc/CU-iter -- block-wide barriers phase-align all waves so pipes don't
// overlap. v12 shrinks the DS term: the channel-split PV means NO wave shares
// V data with another, so V never needed LDS (LDS = cross-wave sharing). V is
// loaded straight to registers (8 x 16B per wave) at iter START and consumed
// at iter END -> ~2.5k-cyc latency window >> L2 latency (v8's mistake was V
// loads ON the PV critical path). Deletes per CU-iter: 64 PV ds_reads, all V
// staging writes. DS ~3.4k -> ~1.9k cyc. LDS 160 -> 96 KB. QK k-split, Sx
// exchange, softmax, pack, PV math, epilogue: v11-validated, byte-identical
// (PV B-operand bytes identical to the old LDS path). ~220 VGPR, 2 waves/SIMD.
__global__ __launch_bounds__(512, 2) void flash_k(const short* __restrict__ Q,
                                                  const short* __restrict__ K,
                                                  const short* __restrict__ Vt,
                                                  short* __restrict__ O) {
  __shared__ __attribute__((aligned(16))) short Ks[2][16384];   // 64 KB
  __shared__ __attribute__((aligned(16))) float Sx[8192];       // 32 KB exchange
  int L = blockIdx.x;
  int b = (L & 7) >> 1;                       // batch -> XCD pair (L%8 round-robin)
  int q0 = (((L >> 3) << 1) | (L & 1)) * 64;
  int tid = threadIdx.x;
  int w = tid >> 6, lane = tid & 63;
  int ql = lane & 31, hi = lane >> 5;
  int qh = w & 1;                             // query half (32 queries)
  int gg = w >> 1;                            // PV channel quarter (128 ch)
  int kj = gg & 1;                            // QK k-split half (256 ch)
  const size_t batch_off = (size_t)b * 4096 * 512;
  const float scale2 = 0.06375872f;           // 512^-0.5 * log2(e)

  // Q fragments (B-operand 32x32x16: col=query=ql, k=hi*8+j), 16 steps = half C
  const short* Qrow = Q + batch_off + (size_t)(q0 + qh * 32 + ql) * 512 + kj * 256;
  bf16x8 qf[16];
#pragma unroll
  for (int s = 0; s < 16; s++)
    qf[s] = *(const bf16x8*)&Qrow[s * 16 + hi * 8];

  const f32x16 fz16 = {0,0,0,0,0,0,0,0,0,0,0,0,0,0,0,0};
  f32x16 oacc[4];                             // 32q x 128ch (quarter gg)
#pragma unroll
  for (int i = 0; i < 4; i++) oacc[i] = fz16;
  float mrun = -1e30f, lrun = 0.f;

  // V direct-load base: lane reads V[ch = gg*128 + cb*32 + ql][t0 + ks*16 + hi*8]
  const short* Vb0 = Vt + batch_off + (size_t)(gg * 128 + ql) * 4096 + hi * 8;

  // ---- prologue: stage K tile 0 into buf 0 (32 slices of 1 KB, 4/wave) ----
#pragma unroll
  for (int i = 0; i < 4; i++) {
    int s = w * 4 + i;                        // K slice = k-step s (1 KB)
    const short* gk = K + batch_off + (size_t)ql * 512 + s * 16 + hi * 8;
    __builtin_amdgcn_global_load_lds((__attribute__((address_space(1))) void*)gk,
                                     (__attribute__((address_space(3))) void*)&Ks[0][s * 512],
                                     16, 0, 0);
  }

#pragma unroll 1
  for (int it = 0; it < 128; ++it) {
    int t0 = it * 32;
    int buf = it & 1;
    __syncthreads();   // K staging of buf drained (vmcnt); all waves done with buf^1
    // ---- V loads for THIS iter: 8 x 16B straight to VGPRs (consumed at PV) ----
    bf16x8 vr[4][2];
#pragma unroll
    for (int cb = 0; cb < 4; cb++)
#pragma unroll
      for (int ks = 0; ks < 2; ks++)
        vr[cb][ks] = *(const bf16x8*)(Vb0 + (size_t)cb * 32 * 4096 + t0 + ks * 16);
    if (it < 127) {
      int t1 = t0 + 32;
#pragma unroll
      for (int i = 0; i < 4; i++) {
        int s = w * 4 + i;
        const short* gk = K + batch_off + (size_t)(t1 + ql) * 512 + s * 16 + hi * 8;
        __builtin_amdgcn_global_load_lds((__attribute__((address_space(1))) void*)gk,
                                         (__attribute__((address_space(3))) void*)&Ks[buf ^ 1][s * 512],
                                         16, 0, 0);
      }
    }
    // ---- QK^T partial (this wave's 256 channels): A=K rows=keys, B=Q ----
    f32x16 sc0 = fz16, sc1 = fz16;
#pragma unroll
    for (int s = 0; s < 16; s += 2) {
      bf16x8 k0 = *(const bf16x8*)&Ks[buf][(kj * 16 + s + 0) * 512 + lane * 8];
      bf16x8 k1 = *(const bf16x8*)&Ks[buf][(kj * 16 + s + 1) * 512 + lane * 8];
      sc0 = __builtin_amdgcn_mfma_f32_32x32x16_bf16(k0, qf[s + 0], sc0, 0, 0, 0);
      sc1 = __builtin_amdgcn_mfma_f32_32x32x16_bf16(k1, qf[s + 1], sc1, 0, 0, 0);
    }
    // ---- exchange partial S with partner wave (w^2): 4 KB each via Sx ----
    f32x4 c[4];
#pragma unroll
    for (int i = 0; i < 4; i++) {
      c[i][0] = sc0[4 * i + 0] + sc1[4 * i + 0];
      c[i][1] = sc0[4 * i + 1] + sc1[4 * i + 1];
      c[i][2] = sc0[4 * i + 2] + sc1[4 * i + 2];
      c[i][3] = sc0[4 * i + 3] + sc1[4 * i + 3];
      *(f32x4*)&Sx[w * 1024 + i * 256 + lane * 4] = c[i];
    }
    asm volatile("s_waitcnt lgkmcnt(0)" ::: "memory");
    __builtin_amdgcn_s_barrier();               // raw: no vmcnt drain (prefetch + V loads stay in flight)
    asm volatile("" ::: "memory");
    // lane holds: query ql, keys crow(r,hi) = (r&3) + 8*(r>>2) + 4*hi
    float pl[16];
#pragma unroll
    for (int i = 0; i < 4; i++) {
      f32x4 d = *(const f32x4*)&Sx[(w ^ 2) * 1024 + i * 256 + lane * 4];
      pl[4 * i + 0] = (c[i][0] + d[0]) * scale2;
      pl[4 * i + 1] = (c[i][1] + d[1]) * scale2;
      pl[4 * i + 2] = (c[i][2] + d[2]) * scale2;
      pl[4 * i + 3] = (c[i][3] + d[3]) * scale2;
    }
    // ---- softmax: lane-local 16-key reduce + cross-half shfl combine ----
    float mx = pl[0];
#pragma unroll
    for (int r = 1; r < 16; r++) mx = fmaxf(mx, pl[r]);
    mx = fmaxf(mx, __shfl_xor(mx, 32, 64));
    // defer-max: only bump running max (and rescale O) on a >8 jump
    if (__any(mx > mrun + 8.0f)) {
      float mn = fmaxf(mrun, mx);
      float alpha = exp2f(mrun - mn);
      mrun = mn;
      lrun *= alpha;
      float al[16];
#pragma unroll
      for (int r = 0; r < 16; r++)
        al[r] = __shfl(alpha, (r & 3) + 8 * (r >> 2) + 4 * hi, 64);
#pragma unroll
      for (int cb = 0; cb < 4; cb++)
#pragma unroll
        for (int r = 0; r < 16; r++) oacc[cb][r] *= al[r];
    }
    float p[16];
    float sum = 0.f;
#pragma unroll
    for (int r = 0; r < 16; r++) {
      p[r] = exp2f(pl[r] - mrun);
      sum += p[r];
    }
    sum += __shfl_xor(sum, 32, 64);
    lrun += sum;
    // ---- P -> A-frags: cvt_pk words + word-level shfl_xor exchange (validated) ----
    bf16x8 af0, af1;
#pragma unroll
    for (int ks = 0; ks < 2; ks++) {
      uint32_t Aw, Bw, Cw, Dw;
      asm("v_cvt_pk_bf16_f32 %0, %1, %2" : "=v"(Aw) : "v"(p[8 * ks + 0]), "v"(p[8 * ks + 1]));
      asm("v_cvt_pk_bf16_f32 %0, %1, %2" : "=v"(Bw) : "v"(p[8 * ks + 2]), "v"(p[8 * ks + 3]));
      asm("v_cvt_pk_bf16_f32 %0, %1, %2" : "=v"(Cw) : "v"(p[8 * ks + 4]), "v"(p[8 * ks + 5]));
      asm("v_cvt_pk_bf16_f32 %0, %1, %2" : "=v"(Dw) : "v"(p[8 * ks + 6]), "v"(p[8 * ks + 7]));
      uint32_t Asw = (uint32_t)__shfl_xor((int)Aw, 32, 64);
      uint32_t Bsw = (uint32_t)__shfl_xor((int)Bw, 32, 64);
      uint32_t Csw = (uint32_t)__shfl_xor((int)Cw, 32, 64);
      uint32_t Dsw = (uint32_t)__shfl_xor((int)Dw, 32, 64);
      u32x4 u;
      u[0] = hi ? Csw : Aw;
      u[1] = hi ? Dsw : Bw;
      u[2] = hi ? Cw : Asw;
      u[3] = hi ? Dw : Bsw;
      if (ks == 0) af0 = __builtin_bit_cast(bf16x8, u);
      else         af1 = __builtin_bit_cast(bf16x8, u);
    }
    // ---- O += P @ V: A=P (rows=queries), B=V from REGISTERS; 4 chains ----
#pragma unroll
    for (int cb = 0; cb < 4; cb++) {
      oacc[cb] = __builtin_amdgcn_mfma_f32_32x32x16_bf16(af0, vr[cb][0], oacc[cb], 0, 0, 0);
      oacc[cb] = __builtin_amdgcn_mfma_f32_32x32x16_bf16(af1, vr[cb][1], oacc[cb], 0, 0, 0);
    }
  }
  // ---- epilogue: O /= l, store bf16 row-major (rows=queries crow(r,hi)) ----
  float invl = 1.f / lrun;
  float ir[16];
#pragma unroll
  for (int r = 0; r < 16; r++)
    ir[r] = __shfl(invl, (r & 3) + 8 * (r >> 2) + 4 * hi, 64);
#pragma unroll
  for (int cb = 0; cb < 4; cb++) {
    int col = gg * 128 + cb * 32 + ql;
#pragma unroll
    for (int r = 0; r < 16; r++) {
      int row = q0 + qh * 32 + (r & 3) + 8 * (r >> 2) + 4 * hi;
      O[batch_off + (size_t)row * 512 + col] = f2bf(oacc[cb][r] * ir[r]);
    }
  }
}

extern "C" void kernel_launch(void* const* d_in, const int* in_sizes, int n_in,
                              void* d_out, int out_size, void* d_ws, size_t ws_size,
                              hipStream_t stream) {
  const float* x  = (const float*)d_in[0];
  const float* gs = (const float*)d_in[1];
  const float* gb = (const float*)d_in[2];
  const float* wq = (const float*)d_in[3];
  const float* bq = (const float*)d_in[4];
  const float* wk = (const float*)d_in[5];
  const float* bk = (const float*)d_in[6];
  const float* wv = (const float*)d_in[7];
  const float* bv = (const float*)d_in[8];
  const float* wp = (const float*)d_in[9];
  const float* bp = (const float*)d_in[10];
  float* out = (float*)d_out;

  // ---- workspace layout (~34 MB; Q/K live in d_out until final GEMM) ----
  char* ws = (char*)d_ws;
  float* mean = (float*)ws;                               // 128 f
  float* rstd = (float*)(ws + 512);                       // 128 f
  short* h    = (short*)(ws + 1024);                      // 16384*512 bf16 (16.78 MB)
  short* wt   = (short*)(ws + 1024 + 16777216);           // 4*512*512 bf16 (2 MB)
  short* Vt   = (short*)(ws + 1024 + 16777216 + 2097152); // [b][c][t] bf16 (16.78 MB)
  short* Qb   = (short*)d_out;                            // 16.78 MB in d_out
  short* Kb   = Qb + 8388608;                             // 16.78 MB in d_out
  short* Ob   = h;                                        // alias: h dead after V GEMM

  gn_stats_k<<<128, 256, 0, stream>>>(x, mean, rstd);
  gn_apply_k<<<8192, 256, 0, stream>>>(x, mean, rstd, gs, gb, h);
  wconv_k<<<4096, 256, 0, stream>>>(wq, wk, wv, wp, wt);
  dim3 gg(128, 4);
  gemm_k<<<gg, 256, 0, stream>>>(h, wt,          bq, nullptr, Qb, nullptr, 0);
  gemm_k<<<gg, 256, 0, stream>>>(h, wt + 262144, bk, nullptr, Kb, nullptr, 0);
  gemm_k<<<gg, 256, 0, stream>>>(h, wt + 524288, bv, nullptr, Vt, nullptr, 1);
  flash_k<<<256, 512, 0, stream>>>(Qb, Kb, Vt, Ob);
  // final projection reads Ob (=h space), x, wt_p; writes d_out (overwrites Q/K)
  gemm_k<<<gg, 256, 0, stream>>>(Ob, wt + 786432, bp, x, nullptr, out, 2);
}

// Round 7
// 577.215 us; speedup vs baseline: 1.5487x; 1.1361x over previous
//
#include <hip/hip_runtime.h>
#include <stdint.h>

// ---------- types ----------
typedef __bf16  bf16x8 __attribute__((ext_vector_type(8)));
typedef short   s16x8  __attribute__((ext_vector_type(8)));
typedef float   f32x4  __attribute__((ext_vector_type(4)));
typedef float   f32x16 __attribute__((ext_vector_type(16)));
typedef uint32_t u32x4 __attribute__((ext_vector_type(4)));

__device__ inline short f2bf(float f) {
  union { float f; uint32_t u; } v; v.f = f;
  uint32_t r = v.u + 0x7FFFu + ((v.u >> 16) & 1u);   // RNE
  return (short)(r >> 16);
}

// B=4, H=W=D=16 -> N=4096 tokens/batch, C=512, GROUPS=32 (16 ch/group)

// ---------- GroupNorm stats ----------
__global__ __launch_bounds__(256) void gn_stats_k(const float* __restrict__ x,
                                                  float* __restrict__ mean,
                                                  float* __restrict__ rstd) {
  int bg = blockIdx.x;
  int b = bg >> 5, g = bg & 31;
  int tid = threadIdx.x;
  const float* base = x + (size_t)b * 4096 * 512 + g * 16;
  float s = 0.f, q = 0.f;
  for (int i = tid; i < 16384; i += 256) {
    int n = i >> 2, sub = i & 3;
    float4 v = *(const float4*)(base + (size_t)n * 512 + sub * 4);
    s += v.x + v.y + v.z + v.w;
    q += v.x * v.x + v.y * v.y + v.z * v.z + v.w * v.w;
  }
  for (int off = 32; off > 0; off >>= 1) {
    s += __shfl_down(s, off, 64);
    q += __shfl_down(q, off, 64);
  }
  __shared__ float rs[4], rq[4];
  int w = tid >> 6;
  if ((tid & 63) == 0) { rs[w] = s; rq[w] = q; }
  __syncthreads();
  if (tid == 0) {
    float S = rs[0] + rs[1] + rs[2] + rs[3];
    float Q = rq[0] + rq[1] + rq[2] + rq[3];
    float m = S * (1.f / 65536.f);
    float var = Q * (1.f / 65536.f) - m * m;
    mean[bg] = m;
    rstd[bg] = rsqrtf(var + 1e-6f);
  }
}

// ---------- GN apply -> bf16 h ----------
__global__ __launch_bounds__(256) void gn_apply_k(const float* __restrict__ x,
                                                  const float* __restrict__ mean,
                                                  const float* __restrict__ rstd,
                                                  const float* __restrict__ sc,
                                                  const float* __restrict__ bi,
                                                  short* __restrict__ h) {
  size_t i4 = ((size_t)blockIdx.x * 256 + threadIdx.x) * 4;
  int c = (int)(i4 & 511);
  int tok = (int)(i4 >> 9);
  int b = tok >> 12;
  int bg = b * 32 + (c >> 4);
  float m = mean[bg], r = rstd[bg];
  float4 v = *(const float4*)(x + i4);
  float4 s = *(const float4*)(sc + c);
  float4 bb = *(const float4*)(bi + c);
  short4 o;
  o.x = f2bf((v.x - m) * r * s.x + bb.x);
  o.y = f2bf((v.y - m) * r * s.y + bb.y);
  o.z = f2bf((v.z - m) * r * s.z + bb.z);
  o.w = f2bf((v.w - m) * r * s.w + bb.w);
  *(short4*)(h + i4) = o;
}

// ---------- weights -> bf16, transposed ----------
__global__ __launch_bounds__(256) void wconv_k(const float* __restrict__ wq,
                                               const float* __restrict__ wk,
                                               const float* __restrict__ wv,
                                               const float* __restrict__ wp,
                                               short* __restrict__ wt) {
  int i = blockIdx.x * 256 + threadIdx.x;
  int widx = i >> 18, rem = i & 262143;
  int c = rem >> 9, j = rem & 511;
  const float* w = widx == 0 ? wq : widx == 1 ? wk : widx == 2 ? wv : wp;
  wt[(size_t)widx * 262144 + (size_t)j * 512 + c] = f2bf(w[(size_t)c * 512 + j]);
}

// ---------- fused Q/K/V GEMM: one dispatch, grid (128, 12) ----------
// blockIdx.y: widx = y>>2 (0=Q,1=K,2=V), n0 = (y&3)*128. Same validated
// 128x128 tile body as gemm_k. Q output pre-scaled by C^-0.5 * log2(e)
// (folds flash's softmax scale into the GEMM epilogue). V written to
// Vt[b][c][t] with short4-vectorized stores (4 contiguous t per thread).
__global__ __launch_bounds__(256) void qkv_gemm_k(const short* __restrict__ A,
                                                  const short* __restrict__ wt,
                                                  const float* __restrict__ bq,
                                                  const float* __restrict__ bk,
                                                  const float* __restrict__ bv,
                                                  short* __restrict__ Qb,
                                                  short* __restrict__ Kb,
                                                  short* __restrict__ Vt) {
  __shared__ __attribute__((aligned(16))) short As[128 * 32];
  __shared__ __attribute__((aligned(16))) short Bs[128 * 32];
  int widx = blockIdx.y >> 2;
  int n0 = (blockIdx.y & 3) * 128;
  const short* Bt = wt + (size_t)widx * 262144;
  const float* bias = widx == 0 ? bq : widx == 1 ? bk : bv;
  const float qscale = widx == 0 ? 0.06375872f : 1.0f;   // 512^-0.5 * log2(e)

  int tid = threadIdx.x;
  int w = tid >> 6, lane = tid & 63, quad = lane >> 4, mrow = lane & 15;
  int wm = w >> 1, wn = w & 1;
  int m0 = blockIdx.x * 128;

  const f32x4 fz = {0.f, 0.f, 0.f, 0.f};
  f32x4 acc[4][4];
#pragma unroll
  for (int i = 0; i < 4; i++)
#pragma unroll
    for (int j = 0; j < 4; j++) acc[i][j] = fz;

  int srow = tid >> 2;
  int scol = (tid & 3) * 8;

  for (int k0 = 0; k0 < 512; k0 += 32) {
    __syncthreads();
#pragma unroll
    for (int i = 0; i < 2; i++) {
      const short* ga = A + (size_t)(m0 + i * 64 + srow) * 512 + k0 + scol;
      const short* gb = Bt + (size_t)(n0 + i * 64 + srow) * 512 + k0 + scol;
      char* la = (char*)As + i * 4096 + w * 1024;
      char* lb = (char*)Bs + i * 4096 + w * 1024;
      __builtin_amdgcn_global_load_lds((__attribute__((address_space(1))) void*)ga,
                                       (__attribute__((address_space(3))) void*)la, 16, 0, 0);
      __builtin_amdgcn_global_load_lds((__attribute__((address_space(1))) void*)gb,
                                       (__attribute__((address_space(3))) void*)lb, 16, 0, 0);
    }
    __syncthreads();
    bf16x8 af[4], bfv[4];
#pragma unroll
    for (int mi = 0; mi < 4; mi++)
      af[mi] = *(const bf16x8*)&As[(wm * 64 + mi * 16 + mrow) * 32 + quad * 8];
#pragma unroll
    for (int ni = 0; ni < 4; ni++)
      bfv[ni] = *(const bf16x8*)&Bs[(wn * 64 + ni * 16 + mrow) * 32 + quad * 8];
#pragma unroll
    for (int mi = 0; mi < 4; mi++)
#pragma unroll
      for (int ni = 0; ni < 4; ni++)
        acc[mi][ni] = __builtin_amdgcn_mfma_f32_16x16x32_bf16(af[mi], bfv[ni], acc[mi][ni], 0, 0, 0);
  }

#pragma unroll
  for (int mi = 0; mi < 4; mi++)
#pragma unroll
    for (int ni = 0; ni < 4; ni++) {
      int col = n0 + wn * 64 + ni * 16 + mrow;
      float bv2 = bias[col];
      if (widx < 2) {
        short* outb = widx ? Kb : Qb;
#pragma unroll
        for (int r = 0; r < 4; r++) {
          int row = m0 + wm * 64 + mi * 16 + quad * 4 + r;
          outb[(size_t)row * 512 + col] = f2bf((acc[mi][ni][r] + bv2) * qscale);
        }
      } else {
        int row0 = m0 + wm * 64 + mi * 16 + quad * 4;
        int b = row0 >> 12, t0 = row0 & 4095;
        short4 o;
        o.x = f2bf(acc[mi][ni][0] + bv2);
        o.y = f2bf(acc[mi][ni][1] + bv2);
        o.z = f2bf(acc[mi][ni][2] + bv2);
        o.w = f2bf(acc[mi][ni][3] + bv2);
        *(short4*)&Vt[(size_t)b * (512 * 4096) + (size_t)col * 4096 + t0] = o;
      }
    }
}

// ---------- GEMM (final projection, validated) ----------
__global__ __launch_bounds__(256) void gemm_k(const short* __restrict__ A,
                                              const short* __restrict__ Bt,
                                              const float* __restrict__ bias,
                                              const float* __restrict__ xres,
                                              short* __restrict__ outb,
                                              float* __restrict__ outf, int mode) {
  __shared__ __attribute__((aligned(16))) short As[128 * 32];
  __shared__ __attribute__((aligned(16))) short Bs[128 * 32];
  int tid = threadIdx.x;
  int w = tid >> 6, lane = tid & 63, quad = lane >> 4, mrow = lane & 15;
  int wm = w >> 1, wn = w & 1;
  int m0 = blockIdx.x * 128, n0 = blockIdx.y * 128;

  const f32x4 fz = {0.f, 0.f, 0.f, 0.f};
  f32x4 acc[4][4];
#pragma unroll
  for (int i = 0; i < 4; i++)
#pragma unroll
    for (int j = 0; j < 4; j++) acc[i][j] = fz;

  int srow = tid >> 2;
  int scol = (tid & 3) * 8;

  for (int k0 = 0; k0 < 512; k0 += 32) {
    __syncthreads();
#pragma unroll
    for (int i = 0; i < 2; i++) {
      const short* ga = A + (size_t)(m0 + i * 64 + srow) * 512 + k0 + scol;
      const short* gb = Bt + (size_t)(n0 + i * 64 + srow) * 512 + k0 + scol;
      char* la = (char*)As + i * 4096 + w * 1024;
      char* lb = (char*)Bs + i * 4096 + w * 1024;
      __builtin_amdgcn_global_load_lds((__attribute__((address_space(1))) void*)ga,
                                       (__attribute__((address_space(3))) void*)la, 16, 0, 0);
      __builtin_amdgcn_global_load_lds((__attribute__((address_space(1))) void*)gb,
                                       (__attribute__((address_space(3))) void*)lb, 16, 0, 0);
    }
    __syncthreads();
    bf16x8 af[4], bfv[4];
#pragma unroll
    for (int mi = 0; mi < 4; mi++)
      af[mi] = *(const bf16x8*)&As[(wm * 64 + mi * 16 + mrow) * 32 + quad * 8];
#pragma unroll
    for (int ni = 0; ni < 4; ni++)
      bfv[ni] = *(const bf16x8*)&Bs[(wn * 64 + ni * 16 + mrow) * 32 + quad * 8];
#pragma unroll
    for (int mi = 0; mi < 4; mi++)
#pragma unroll
      for (int ni = 0; ni < 4; ni++)
        acc[mi][ni] = __builtin_amdgcn_mfma_f32_16x16x32_bf16(af[mi], bfv[ni], acc[mi][ni], 0, 0, 0);
  }

#pragma unroll
  for (int mi = 0; mi < 4; mi++)
#pragma unroll
    for (int ni = 0; ni < 4; ni++) {
      int col = n0 + wn * 64 + ni * 16 + mrow;
      float bv = bias[col];
#pragma unroll
      for (int r = 0; r < 4; r++) {
        int row = m0 + wm * 64 + mi * 16 + quad * 4 + r;
        float val = acc[mi][ni][r] + bv;
        if (mode == 0) {
          outb[(size_t)row * 512 + col] = f2bf(val);
        } else if (mode == 1) {
          int b = row >> 12, t = row & 4095;
          outb[(size_t)b * (512 * 4096) + (size_t)col * 4096 + t] = f2bf(val);
        } else {
          size_t idx = (size_t)row * 512 + col;
          outf[idx] = xres[idx] + val;
        }
      }
    }
}

// ---------- flash attention v13: v12 + SINGLE barrier/iter (counted vmcnt) ----------
// v12 = 454us, 2 barrier convoys/iter (syncthreads top w/ vmcnt(0) drain + raw
// Sx barrier). v13 merges them into ONE raw barrier (T3/T4 counted-vmcnt):
//   iter i: issue K-staging(buf^1) -> fence -> V loads(8) -> QK (staging
//   latency hides under ~1.5k cyc of ds_read+MFMA) -> Sx[i&1] write ->
//   s_waitcnt lgkmcnt(0) vmcnt(8) -> s_barrier -> softmax/pack/PV.
// Correctness: staging(i)->buf^1 ordered after reads(i-1) by barrier(i-1);
// vmcnt(8) drains staging (the 8 allowed = this iter's V loads, issued after
// staging behind a fence) before the barrier publishes; Sx double-buffered so
// read(i) vs write(i+2) are separated by barrier(i+1). Also: QK now 4 MFMA
// chains (depth 4) and softmax scale pre-folded into Q (GEMM epilogue).
__global__ __launch_bounds__(512, 2) void flash_k(const short* __restrict__ Q,
                                                  const short* __restrict__ K,
                                                  const short* __restrict__ Vt,
                                                  short* __restrict__ O) {
  __shared__ __attribute__((aligned(16))) short Ks[2][16384];   // 64 KB
  __shared__ __attribute__((aligned(16))) float Sx[2][8192];    // 64 KB exchange (dbuf)
  int L = blockIdx.x;
  int b = (L & 7) >> 1;                       // batch -> XCD pair (L%8 round-robin)
  int q0 = (((L >> 3) << 1) | (L & 1)) * 64;
  int tid = threadIdx.x;
  int w = tid >> 6, lane = tid & 63;
  int ql = lane & 31, hi = lane >> 5;
  int qh = w & 1;                             // query half (32 queries)
  int gg = w >> 1;                            // PV channel quarter (128 ch)
  int kj = gg & 1;                            // QK k-split half (256 ch)
  const size_t batch_off = (size_t)b * 4096 * 512;

  // Q fragments (B-operand 32x32x16: col=query=ql, k=hi*8+j); Q is pre-scaled
  const short* Qrow = Q + batch_off + (size_t)(q0 + qh * 32 + ql) * 512 + kj * 256;
  bf16x8 qf[16];
#pragma unroll
  for (int s = 0; s < 16; s++)
    qf[s] = *(const bf16x8*)&Qrow[s * 16 + hi * 8];

  const f32x16 fz16 = {0,0,0,0,0,0,0,0,0,0,0,0,0,0,0,0};
  f32x16 oacc[4];                             // 32q x 128ch (quarter gg)
#pragma unroll
  for (int i = 0; i < 4; i++) oacc[i] = fz16;
  float mrun = -1e30f, lrun = 0.f;

  // V direct-load base: lane reads V[ch = gg*128 + cb*32 + ql][t0 + ks*16 + hi*8]
  const short* Vb0 = Vt + batch_off + (size_t)(gg * 128 + ql) * 4096 + hi * 8;

  // ---- prologue: stage K tile 0 into buf 0 (32 slices of 1 KB, 4/wave) ----
#pragma unroll
  for (int i = 0; i < 4; i++) {
    int s = w * 4 + i;                        // K slice = k-step s (1 KB)
    const short* gk = K + batch_off + (size_t)ql * 512 + s * 16 + hi * 8;
    __builtin_amdgcn_global_load_lds((__attribute__((address_space(1))) void*)gk,
                                     (__attribute__((address_space(3))) void*)&Ks[0][s * 512],
                                     16, 0, 0);
  }
  __syncthreads();                            // one-time full drain

#pragma unroll 1
  for (int it = 0; it < 128; ++it) {
    int t0 = it * 32;
    int buf = it & 1;
    // ---- issue next K tile FIRST (drained by vmcnt(8) at this iter's barrier) ----
    if (it < 127) {
      int t1 = t0 + 32;
#pragma unroll
      for (int i = 0; i < 4; i++) {
        int s = w * 4 + i;
        const short* gk = K + batch_off + (size_t)(t1 + ql) * 512 + s * 16 + hi * 8;
        __builtin_amdgcn_global_load_lds((__attribute__((address_space(1))) void*)gk,
                                         (__attribute__((address_space(3))) void*)&Ks[buf ^ 1][s * 512],
                                         16, 0, 0);
      }
    }
    asm volatile("" ::: "memory");            // staging precedes V loads in vmem order
    // ---- V loads for THIS iter: 8 x 16B straight to VGPRs (consumed at PV) ----
    bf16x8 vr[4][2];
#pragma unroll
    for (int cb = 0; cb < 4; cb++)
#pragma unroll
      for (int ks = 0; ks < 2; ks++)
        vr[cb][ks] = *(const bf16x8*)(Vb0 + (size_t)cb * 32 * 4096 + t0 + ks * 16);
    // ---- QK^T partial (this wave's 256 channels): A=K rows=keys, B=Q; 4 chains ----
    f32x16 s0 = fz16, s1 = fz16, s2 = fz16, s3 = fz16;
#pragma unroll
    for (int s = 0; s < 16; s += 4) {
      bf16x8 k0 = *(const bf16x8*)&Ks[buf][(kj * 16 + s + 0) * 512 + lane * 8];
      bf16x8 k1 = *(const bf16x8*)&Ks[buf][(kj * 16 + s + 1) * 512 + lane * 8];
      bf16x8 k2 = *(const bf16x8*)&Ks[buf][(kj * 16 + s + 2) * 512 + lane * 8];
      bf16x8 k3 = *(const bf16x8*)&Ks[buf][(kj * 16 + s + 3) * 512 + lane * 8];
      s0 = __builtin_amdgcn_mfma_f32_32x32x16_bf16(k0, qf[s + 0], s0, 0, 0, 0);
      s1 = __builtin_amdgcn_mfma_f32_32x32x16_bf16(k1, qf[s + 1], s1, 0, 0, 0);
      s2 = __builtin_amdgcn_mfma_f32_32x32x16_bf16(k2, qf[s + 2], s2, 0, 0, 0);
      s3 = __builtin_amdgcn_mfma_f32_32x32x16_bf16(k3, qf[s + 3], s3, 0, 0, 0);
    }
    // ---- write partial S for partner wave (w^2) into Sx[buf] ----
    f32x4 c[4];
#pragma unroll
    for (int i = 0; i < 4; i++) {
      c[i][0] = (s0[4 * i + 0] + s1[4 * i + 0]) + (s2[4 * i + 0] + s3[4 * i + 0]);
      c[i][1] = (s0[4 * i + 1] + s1[4 * i + 1]) + (s2[4 * i + 1] + s3[4 * i + 1]);
      c[i][2] = (s0[4 * i + 2] + s1[4 * i + 2]) + (s2[4 * i + 2] + s3[4 * i + 2]);
      c[i][3] = (s0[4 * i + 3] + s1[4 * i + 3]) + (s2[4 * i + 3] + s3[4 * i + 3]);
      *(f32x4*)&Sx[buf][w * 1024 + i * 256 + lane * 4] = c[i];
    }
    // ---- THE barrier: Sx visible (lgkm), K staging landed (vmcnt<=8 = V only) ----
    asm volatile("s_waitcnt lgkmcnt(0) vmcnt(8)" ::: "memory");
    __builtin_amdgcn_s_barrier();
    asm volatile("" ::: "memory");
    // lane holds: query ql, keys crow(r,hi) = (r&3) + 8*(r>>2) + 4*hi
    float pl[16];
#pragma unroll
    for (int i = 0; i < 4; i++) {
      f32x4 d = *(const f32x4*)&Sx[buf][(w ^ 2) * 1024 + i * 256 + lane * 4];
      pl[4 * i + 0] = c[i][0] + d[0];
      pl[4 * i + 1] = c[i][1] + d[1];
      pl[4 * i + 2] = c[i][2] + d[2];
      pl[4 * i + 3] = c[i][3] + d[3];
    }
    // ---- softmax: lane-local 16-key reduce + cross-half shfl combine ----
    float mx = pl[0];
#pragma unroll
    for (int r = 1; r < 16; r++) mx = fmaxf(mx, pl[r]);
    mx = fmaxf(mx, __shfl_xor(mx, 32, 64));
    // defer-max: only bump running max (and rescale O) on a >8 jump
    if (__any(mx > mrun + 8.0f)) {
      float mn = fmaxf(mrun, mx);
      float alpha = exp2f(mrun - mn);
      mrun = mn;
      lrun *= alpha;
      float al[16];
#pragma unroll
      for (int r = 0; r < 16; r++)
        al[r] = __shfl(alpha, (r & 3) + 8 * (r >> 2) + 4 * hi, 64);
#pragma unroll
      for (int cb = 0; cb < 4; cb++)
#pragma unroll
        for (int r = 0; r < 16; r++) oacc[cb][r] *= al[r];
    }
    float p[16];
    float sum = 0.f;
#pragma unroll
    for (int r = 0; r < 16; r++) {
      p[r] = exp2f(pl[r] - mrun);
      sum += p[r];
    }
    sum += __shfl_xor(sum, 32, 64);
    lrun += sum;
    // ---- P -> A-frags: cvt_pk words + word-level shfl_xor exchange (validated) ----
    bf16x8 af0, af1;
#pragma unroll
    for (int ks = 0; ks < 2; ks++) {
      uint32_t Aw, Bw, Cw, Dw;
      asm("v_cvt_pk_bf16_f32 %0, %1, %2" : "=v"(Aw) : "v"(p[8 * ks + 0]), "v"(p[8 * ks + 1]));
      asm("v_cvt_pk_bf16_f32 %0, %1, %2" : "=v"(Bw) : "v"(p[8 * ks + 2]), "v"(p[8 * ks + 3]));
      asm("v_cvt_pk_bf16_f32 %0, %1, %2" : "=v"(Cw) : "v"(p[8 * ks + 4]), "v"(p[8 * ks + 5]));
      asm("v_cvt_pk_bf16_f32 %0, %1, %2" : "=v"(Dw) : "v"(p[8 * ks + 6]), "v"(p[8 * ks + 7]));
      uint32_t Asw = (uint32_t)__shfl_xor((int)Aw, 32, 64);
      uint32_t Bsw = (uint32_t)__shfl_xor((int)Bw, 32, 64);
      uint32_t Csw = (uint32_t)__shfl_xor((int)Cw, 32, 64);
      uint32_t Dsw = (uint32_t)__shfl_xor((int)Dw, 32, 64);
      u32x4 u;
      u[0] = hi ? Csw : Aw;
      u[1] = hi ? Dsw : Bw;
      u[2] = hi ? Cw : Asw;
      u[3] = hi ? Dw : Bsw;
      if (ks == 0) af0 = __builtin_bit_cast(bf16x8, u);
      else         af1 = __builtin_bit_cast(bf16x8, u);
    }
    // ---- O += P @ V: A=P (rows=queries), B=V from REGISTERS; 4 chains ----
#pragma unroll
    for (int cb = 0; cb < 4; cb++) {
      oacc[cb] = __builtin_amdgcn_mfma_f32_32x32x16_bf16(af0, vr[cb][0], oacc[cb], 0, 0, 0);
      oacc[cb] = __builtin_amdgcn_mfma_f32_32x32x16_bf16(af1, vr[cb][1], oacc[cb], 0, 0, 0);
    }
  }
  // ---- epilogue: O /= l, store bf16 row-major (rows=queries crow(r,hi)) ----
  float invl = 1.f / lrun;
  float ir[16];
#pragma unroll
  for (int r = 0; r < 16; r++)
    ir[r] = __shfl(invl, (r & 3) + 8 * (r >> 2) + 4 * hi, 64);
#pragma unroll
  for (int cb = 0; cb < 4; cb++) {
    int col = gg * 128 + cb * 32 + ql;
#pragma unroll
    for (int r = 0; r < 16; r++) {
      int row = q0 + qh * 32 + (r & 3) + 8 * (r >> 2) + 4 * hi;
      O[batch_off + (size_t)row * 512 + col] = f2bf(oacc[cb][r] * ir[r]);
    }
  }
}

extern "C" void kernel_launch(void* const* d_in, const int* in_sizes, int n_in,
                              void* d_out, int out_size, void* d_ws, size_t ws_size,
                              hipStream_t stream) {
  const float* x  = (const float*)d_in[0];
  const float* gs = (const float*)d_in[1];
  const float* gb = (const float*)d_in[2];
  const float* wq = (const float*)d_in[3];
  const float* bq = (const float*)d_in[4];
  const float* wk = (const float*)d_in[5];
  const float* bk = (const float*)d_in[6];
  const float* wv = (const float*)d_in[7];
  const float* bv = (const float*)d_in[8];
  const float* wp = (const float*)d_in[9];
  const float* bp = (const float*)d_in[10];
  float* out = (float*)d_out;

  // ---- workspace layout (~34 MB; Q/K live in d_out until final GEMM) ----
  char* ws = (char*)d_ws;
  float* mean = (float*)ws;                               // 128 f
  float* rstd = (float*)(ws + 512);                       // 128 f
  short* h    = (short*)(ws + 1024);                      // 16384*512 bf16 (16.78 MB)
  short* wt   = (short*)(ws + 1024 + 16777216);           // 4*512*512 bf16 (2 MB)
  short* Vt   = (short*)(ws + 1024 + 16777216 + 2097152); // [b][c][t] bf16 (16.78 MB)
  short* Qb   = (short*)d_out;                            // 16.78 MB in d_out
  short* Kb   = Qb + 8388608;                             // 16.78 MB in d_out
  short* Ob   = h;                                        // alias: h dead after V GEMM

  gn_stats_k<<<128, 256, 0, stream>>>(x, mean, rstd);
  gn_apply_k<<<8192, 256, 0, stream>>>(x, mean, rstd, gs, gb, h);
  wconv_k<<<4096, 256, 0, stream>>>(wq, wk, wv, wp, wt);
  qkv_gemm_k<<<dim3(128, 12), 256, 0, stream>>>(h, wt, bq, bk, bv, Qb, Kb, Vt);
  flash_k<<<256, 512, 0, stream>>>(Qb, Kb, Vt, Ob);
  // final projection reads Ob (=h space), x, wt_p; writes d_out (overwrites Q/K)
  gemm_k<<<dim3(128, 4), 256, 0, stream>>>(Ob, wt + 786432, bp, x, nullptr, out, 2);
}